// Round 5
// baseline (5108.264 us; speedup 1.0000x reference)
//
#include <hip/hip_runtime.h>
#include <cstdio>

#define NH 16
#define DK 64
#define SEQ 2048
#define DMODEL 1024
#define BATCH 2
#define MROWS (BATCH * SEQ) /* 4096 */

// ---------------------------------------------------------------- f32 GEMM
// C[4096,1024] = A[4096,1024] @ W[1024,1024]^T + bias.  64x64 tile, 16 k-chunk.
__global__ __launch_bounds__(256) void gemm_f32(const float* __restrict__ A,
                                                const float* __restrict__ W,
                                                const float* __restrict__ bias,
                                                float* __restrict__ C) {
  __shared__ float As[64][20];   // 80B rows: float4-aligned, banks spread
  __shared__ float Ws[64][20];
  const int t  = threadIdx.x;
  const int tm = t >> 4, tn = t & 15;       // 16x16 thread grid
  const int nb = blockIdx.x & 15;           // N/64 = 16
  const int mb = blockIdx.x >> 4;           // M/64 = 64
  const int lrow = t >> 2;                  // 0..63 (staging row)
  const int lcol = (t & 3) << 2;            // 0,4,8,12 (staging col)

  float acc[4][4] = {};

  for (int kt = 0; kt < DMODEL; kt += 16) {
    __syncthreads();
    float4 va = *(const float4*)(A + (long)(mb * 64 + lrow) * DMODEL + kt + lcol);
    float4 vw = *(const float4*)(W + (long)(nb * 64 + lrow) * DMODEL + kt + lcol);
    *(float4*)(&As[lrow][lcol]) = va;
    *(float4*)(&Ws[lrow][lcol]) = vw;
    __syncthreads();
#pragma unroll
    for (int kk = 0; kk < 16; ++kk) {
      float a4[4], w4[4];
#pragma unroll
      for (int i = 0; i < 4; ++i) a4[i] = As[tm * 4 + i][kk];
#pragma unroll
      for (int j = 0; j < 4; ++j) w4[j] = Ws[tn * 4 + j][kk];
#pragma unroll
      for (int i = 0; i < 4; ++i)
#pragma unroll
        for (int j = 0; j < 4; ++j) acc[i][j] += a4[i] * w4[j];
    }
  }

#pragma unroll
  for (int i = 0; i < 4; ++i) {
    int m = mb * 64 + tm * 4 + i;
#pragma unroll
    for (int j = 0; j < 4; ++j) {
      int n = nb * 64 + tn * 4 + j;
      C[(long)m * DMODEL + n] = acc[i][j] + bias[n];
    }
  }
}

// ---------------------------------------------------------------- f32 attention
// One thread per (b,h,q). Q/K/V row-major [B*S,1024], head h at cols h*64..
// Direct int32 mask. f32 online softmax. Out row-major [B*S,1024].
__global__ __launch_bounds__(256) void attn_f32(const float* __restrict__ Qp,
                                                const float* __restrict__ Kp,
                                                const float* __restrict__ Vp,
                                                const int* __restrict__ mask,
                                                float* __restrict__ Ab) {
  int tid = blockIdx.x * blockDim.x + threadIdx.x;   // 0..65535
  int bh  = tid >> 11;
  int q   = tid & 2047;
  int b   = bh >> 4, h = bh & 15;
  const long rowQ = ((long)(b * SEQ + q)) * DMODEL + h * DK;

  float qv[DK];
#pragma unroll
  for (int i = 0; i < 16; ++i) {
    float4 v = *(const float4*)(Qp + rowQ + i * 4);
    qv[i * 4 + 0] = v.x; qv[i * 4 + 1] = v.y; qv[i * 4 + 2] = v.z; qv[i * 4 + 3] = v.w;
  }
  const int*   mrow  = mask + ((long)b * SEQ + q) * SEQ;
  const float* Kbase = Kp + (long)b * SEQ * DMODEL + h * DK;
  const float* Vbase = Vp + (long)b * SEQ * DMODEL + h * DK;

  float m = -3.0e38f, l = 0.f;
  float o[DK];
#pragma unroll
  for (int d = 0; d < DK; ++d) o[d] = 0.f;

  for (int kv = 0; kv < SEQ; ++kv) {
    const float* kr = Kbase + (long)kv * DMODEL;
    float dot = 0.f;
#pragma unroll
    for (int i = 0; i < 16; ++i) {
      float4 v = *(const float4*)(kr + i * 4);
      dot += qv[i * 4] * v.x + qv[i * 4 + 1] * v.y + qv[i * 4 + 2] * v.z + qv[i * 4 + 3] * v.w;
    }
    float s = mrow[kv] ? dot * 0.125f : -1e9f;   // 1/sqrt(64), mask==0 -> -1e9
    if (s > m) {                 // new running max: rescale state
      float c = __expf(m - s);   // first iteration: exp(-huge) = 0
      l *= c;
#pragma unroll
      for (int d = 0; d < DK; ++d) o[d] *= c;
      m = s;
    }
    float p = __expf(s - m);
    l += p;
    const float* vr = Vbase + (long)kv * DMODEL;
#pragma unroll
    for (int i = 0; i < 16; ++i) {
      float4 v = *(const float4*)(vr + i * 4);
      o[i * 4 + 0] += p * v.x; o[i * 4 + 1] += p * v.y;
      o[i * 4 + 2] += p * v.z; o[i * 4 + 3] += p * v.w;
    }
  }
  float inv = 1.0f / l;
  float* orow = Ab + rowQ;
#pragma unroll
  for (int d = 0; d < DK; ++d) orow[d] = o[d] * inv;
}

// ---------------------------------------------------------------- launch
extern "C" void kernel_launch(void* const* d_in, const int* in_sizes, int n_in,
                              void* d_out, int out_size, void* d_ws, size_t ws_size,
                              hipStream_t stream) {
  const float* query = (const float*)d_in[0];
  const float* key   = (const float*)d_in[1];
  const float* value = (const float*)d_in[2];
  const int*   maskp = (const int*)d_in[3];
  const float* Wq = (const float*)d_in[4];
  const float* bq = (const float*)d_in[5];
  const float* Wk = (const float*)d_in[6];
  const float* bk = (const float*)d_in[7];
  const float* Wv = (const float*)d_in[8];
  const float* bv = (const float*)d_in[9];
  const float* Wo = (const float*)d_in[10];
  const float* bo = (const float*)d_in[11];
  float* out = (float*)d_out;

  fprintf(stderr, "[kernel_launch] f32 pipeline; ws=%zu out=%d\n", ws_size, out_size);

  char* ws = (char*)d_ws;
  const long MB = 1 << 20;
  float* Qb = (float*)(ws + 0 * MB);    // 16 MB each
  float* Kb = (float*)(ws + 16 * MB);
  float* Vb = (float*)(ws + 32 * MB);
  float* Ab = (float*)(ws + 48 * MB);

  // projections -> row-major [4096,1024] f32
  gemm_f32<<<1024, 256, 0, stream>>>(query, Wq, bq, Qb);
  gemm_f32<<<1024, 256, 0, stream>>>(key,   Wk, bk, Kb);
  gemm_f32<<<1024, 256, 0, stream>>>(value, Wv, bv, Vb);

  // attention: 65536 threads, one per (b,h,q)
  attn_f32<<<256, 256, 0, stream>>>(Qb, Kb, Vb, maskp, Ab);

  // output projection -> f32 d_out
  gemm_f32<<<1024, 256, 0, stream>>>(Ab, Wo, bo, out);
}

// Round 6
// 314.730 us; speedup vs baseline: 16.2306x; 16.2306x over previous
//
#include <hip/hip_runtime.h>
#include <hip/hip_bf16.h>

#define NH 16
#define DK 64
#define SEQ 2048
#define DMODEL 1024
#define BATCH 2
#define MROWS (BATCH * SEQ) /* 4096 */

using bf16x8 = __attribute__((ext_vector_type(8))) short;
using f32x4  = __attribute__((ext_vector_type(4))) float;

#define NEGI (-1e30f)

static __device__ __forceinline__ unsigned short f2bf(float x) {
  unsigned u = __builtin_bit_cast(unsigned, x);
  u += 0x7fffu + ((u >> 16) & 1u);   // RNE
  return (unsigned short)(u >> 16);
}
static __device__ __forceinline__ float bf2f(unsigned short h) {
  unsigned u = ((unsigned)h) << 16;
  return __builtin_bit_cast(float, u);
}

// ------------------------------------------------- convert f32 -> bf16 (8/thread)
__global__ __launch_bounds__(256) void convert_f2b(const float* __restrict__ src,
                                                   unsigned short* __restrict__ dst,
                                                   long n8) {  // n/8
  long i0 = (long)blockIdx.x * blockDim.x + threadIdx.x;
  long stride = (long)gridDim.x * blockDim.x;
  for (long i = i0; i < n8; i += stride) {
    const float* s = src + i * 8;
    float4 a = *(const float4*)(s);
    float4 b = *(const float4*)(s + 4);
    bf16x8 v;
    v[0] = (short)f2bf(a.x); v[1] = (short)f2bf(a.y);
    v[2] = (short)f2bf(a.z); v[3] = (short)f2bf(a.w);
    v[4] = (short)f2bf(b.x); v[5] = (short)f2bf(b.y);
    v[6] = (short)f2bf(b.z); v[7] = (short)f2bf(b.w);
    *(bf16x8*)(dst + i * 8) = v;
  }
}

// ---------------------------------------------------------------- pack mask
// mask int32 [B,S,S] (0/1) -> packed bits [B*S, S/64] u64, bit i = kv i  (validated r3/r4)
__global__ __launch_bounds__(256) void pack_mask(const int* __restrict__ mask,
                                                 unsigned long long* __restrict__ pm,
                                                 int nwords) {
  int wid  = (blockIdx.x * blockDim.x + threadIdx.x) >> 6;
  int lane = threadIdx.x & 63;
  int nw   = (gridDim.x * blockDim.x) >> 6;
  for (int w = wid; w < nwords; w += nw) {
    int v = mask[(long)w * 64 + lane];
    unsigned long long b = __ballot(v != 0);
    if (lane == 0) pm[w] = b;
  }
}

// ---------------------------------------------------------------- GEMM  C = A @ W^T + bias
// A [4096,1024] bf16, W [1024,1024] bf16 row=out-feature, bias bf16.
// mode 1: scatter bf16 to [B,H,S,dk].  mode 0: row-major f32 (final output).
#define BK 32
#define LDA_ 40

__global__ __launch_bounds__(256) void gemm_bt(const unsigned short* __restrict__ A,
                                               const unsigned short* __restrict__ W,
                                               const unsigned short* __restrict__ bias,
                                               void* __restrict__ Cv,
                                               int mode) {
  __shared__ unsigned short Al[128 * LDA_];
  __shared__ unsigned short Bl[128 * LDA_];
  const int t    = threadIdx.x;
  const int lane = t & 63;
  const int w    = t >> 6;
  const int wm   = w >> 1, wn = w & 1;
  const int g    = lane >> 4, lr = lane & 15;
  const int nb   = blockIdx.x & 7;
  const int mb   = blockIdx.x >> 3;
  const long Abase = (long)mb * 128 * 1024;
  const long Wbase = (long)nb * 128 * 1024;

  f32x4 acc[4][4] = {};

  for (int kt = 0; kt < 1024; kt += BK) {
    __syncthreads();
#pragma unroll
    for (int q = 0; q < 2; ++q) {
      int id  = q * 256 + t;
      int row = id >> 2;
      int c8  = (id & 3) << 3;
      bf16x8 va = *(const bf16x8*)(A + Abase + (long)row * 1024 + kt + c8);
      bf16x8 vb = *(const bf16x8*)(W + Wbase + (long)row * 1024 + kt + c8);
      *(bf16x8*)(&Al[row * LDA_ + c8]) = va;
      *(bf16x8*)(&Bl[row * LDA_ + c8]) = vb;
    }
    __syncthreads();
    bf16x8 af[4], bfr[4];
#pragma unroll
    for (int i = 0; i < 4; ++i) {
      af[i]  = *(const bf16x8*)(&Al[(wm * 64 + i * 16 + lr) * LDA_ + g * 8]);
      bfr[i] = *(const bf16x8*)(&Bl[(wn * 64 + i * 16 + lr) * LDA_ + g * 8]);
    }
#pragma unroll
    for (int i = 0; i < 4; ++i)
#pragma unroll
      for (int j = 0; j < 4; ++j)
        acc[i][j] = __builtin_amdgcn_mfma_f32_16x16x32_bf16(af[i], bfr[j], acc[i][j], 0, 0, 0);
  }

#pragma unroll
  for (int j = 0; j < 4; ++j) {
    int n = nb * 128 + wn * 64 + j * 16 + lr;
    float bv = bf2f(bias[n]);
#pragma unroll
    for (int i = 0; i < 4; ++i) {
#pragma unroll
      for (int r = 0; r < 4; ++r) {
        int m = mb * 128 + wm * 64 + i * 16 + g * 4 + r;
        float v = acc[i][j][r] + bv;
        if (mode == 1) {
          int b = m >> 11, s = m & (SEQ - 1);
          int h = n >> 6, d = n & (DK - 1);
          ((unsigned short*)Cv)[(((long)(b * NH + h) * SEQ + s) << 6) + d] = f2bf(v);
        } else {
          ((float*)Cv)[(long)m * DMODEL + n] = v;
        }
      }
    }
  }
}

// ---------------------------------------------------------------- attention (validated r3)
// Q,K,V [B,H,S,64] bf16. pm [B*S,32] u64. O -> [B,S,1024] bf16.
#define KVB 64
#define LD 72

__global__ __launch_bounds__(256) void attn(const unsigned short* __restrict__ Q,
                                            const unsigned short* __restrict__ K,
                                            const unsigned short* __restrict__ V,
                                            const unsigned long long* __restrict__ pm,
                                            unsigned short* __restrict__ O) {
  __shared__ unsigned short Kl[KVB * LD];
  __shared__ unsigned short Vt[DK * LD];
  __shared__ unsigned short Pl[4][16 * LD];
  const int t    = threadIdx.x;
  const int lane = t & 63;
  const int w    = t >> 6;
  const int g    = lane >> 4, lr = lane & 15;
  const int qb   = blockIdx.x & 31;
  const int bh   = blockIdx.x >> 5;
  const int b    = bh >> 4, h = bh & 15;
  const long base = (long)bh * SEQ * DK;
  const int q0   = qb * 64 + w * 16;

  bf16x8 qf[2];
  {
    const unsigned short* qp = Q + base + (long)(q0 + lr) * DK;
    qf[0] = *(const bf16x8*)(qp + g * 8);
    qf[1] = *(const bf16x8*)(qp + 32 + g * 8);
  }
  float mrun[4], lrun[4];
  f32x4 o[4] = {};
#pragma unroll
  for (int r = 0; r < 4; ++r) { mrun[r] = NEGI; lrun[r] = 0.f; }
  const float scale = 0.125f;

  for (int kt = 0; kt < SEQ / KVB; ++kt) {
    const int kvbase = kt * KVB;
    __syncthreads();
#pragma unroll
    for (int p = 0; p < 2; ++p) {
      int id  = p * 256 + t;
      int row = id >> 3;
      int c8  = (id & 7) << 3;
      bf16x8 kv8 = *(const bf16x8*)(K + base + (long)(kvbase + row) * DK + c8);
      *(bf16x8*)(&Kl[row * LD + c8]) = kv8;
    }
#pragma unroll
    for (int p = 0; p < 2; ++p) {
      int d0 = (w + p * 4) * 8;
      bf16x8 vv = *(const bf16x8*)(V + base + (long)(kvbase + lane) * DK + d0);
#pragma unroll
      for (int e = 0; e < 8; ++e) Vt[(d0 + e) * LD + lane] = (unsigned short)vv[e];
    }
    __syncthreads();

    unsigned long long mw[4];
#pragma unroll
    for (int r = 0; r < 4; ++r) {
      int q = q0 + g * 4 + r;
      mw[r] = pm[((long)b * SEQ + q) * 32 + kt];
    }

    f32x4 sc[4];
#pragma unroll
    for (int c = 0; c < 4; ++c) {
      f32x4 a = {};
      bf16x8 kf0 = *(const bf16x8*)(&Kl[(c * 16 + lr) * LD + g * 8]);
      bf16x8 kf1 = *(const bf16x8*)(&Kl[(c * 16 + lr) * LD + 32 + g * 8]);
      a = __builtin_amdgcn_mfma_f32_16x16x32_bf16(qf[0], kf0, a, 0, 0, 0);
      a = __builtin_amdgcn_mfma_f32_16x16x32_bf16(qf[1], kf1, a, 0, 0, 0);
      sc[c] = a;
    }
    float s[4][4];
#pragma unroll
    for (int c = 0; c < 4; ++c)
#pragma unroll
      for (int r = 0; r < 4; ++r) {
        int bit = c * 16 + lr;
        s[c][r] = ((mw[r] >> bit) & 1ull) ? sc[c][r] * scale : -1e9f;
      }
    float pf[4][4];
#pragma unroll
    for (int r = 0; r < 4; ++r) {
      float mx = fmaxf(fmaxf(s[0][r], s[1][r]), fmaxf(s[2][r], s[3][r]));
#pragma unroll
      for (int off = 1; off < 16; off <<= 1) mx = fmaxf(mx, __shfl_xor(mx, off, 64));
      float mn   = fmaxf(mrun[r], mx);
      float corr = __expf(mrun[r] - mn);
      mrun[r]    = mn;
      float rs = 0.f;
#pragma unroll
      for (int c = 0; c < 4; ++c) {
        float p_  = __expf(s[c][r] - mn);
        pf[c][r]  = p_;
        rs       += p_;
      }
#pragma unroll
      for (int off = 1; off < 16; off <<= 1) rs += __shfl_xor(rs, off, 64);
      lrun[r] = lrun[r] * corr + rs;
#pragma unroll
      for (int dt = 0; dt < 4; ++dt) o[dt][r] *= corr;
    }
    unsigned short* P = &Pl[w][0];
#pragma unroll
    for (int c = 0; c < 4; ++c)
#pragma unroll
      for (int r = 0; r < 4; ++r) P[(g * 4 + r) * LD + c * 16 + lr] = f2bf(pf[c][r]);
    __syncthreads();   // fence u16 stores vs bf16x8 reads
#pragma unroll
    for (int c32 = 0; c32 < 2; ++c32) {
      bf16x8 pfrag = *(const bf16x8*)(&P[lr * LD + c32 * 32 + g * 8]);
#pragma unroll
      for (int dt = 0; dt < 4; ++dt) {
        bf16x8 vf = *(const bf16x8*)(&Vt[(dt * 16 + lr) * LD + c32 * 32 + g * 8]);
        o[dt] = __builtin_amdgcn_mfma_f32_16x16x32_bf16(pfrag, vf, o[dt], 0, 0, 0);
      }
    }
  }
#pragma unroll
  for (int r = 0; r < 4; ++r) {
    float inv = 1.0f / lrun[r];
    int q = q0 + g * 4 + r;
    unsigned short* op = O + ((long)(b * SEQ + q) * DMODEL) + h * DK;
#pragma unroll
    for (int dt = 0; dt < 4; ++dt) op[dt * 16 + lr] = f2bf(o[dt][r] * inv);
  }
}

// ---------------------------------------------------------------- launch
extern "C" void kernel_launch(void* const* d_in, const int* in_sizes, int n_in,
                              void* d_out, int out_size, void* d_ws, size_t ws_size,
                              hipStream_t stream) {
  const int* maskp = (const int*)d_in[3];
  float* out = (float*)d_out;

  char* ws = (char*)d_ws;
  const long MB = 1 << 20;
  unsigned long long* pm = (unsigned long long*)ws;             // 1 MB
  unsigned short* Qc  = (unsigned short*)(ws + 1 * MB);         // 8 MB each
  unsigned short* Kc  = (unsigned short*)(ws + 9 * MB);
  unsigned short* Vc  = (unsigned short*)(ws + 17 * MB);
  unsigned short* Wqc = (unsigned short*)(ws + 25 * MB);        // 2 MB each
  unsigned short* Wkc = (unsigned short*)(ws + 27 * MB);
  unsigned short* Wvc = (unsigned short*)(ws + 29 * MB);
  unsigned short* Woc = (unsigned short*)(ws + 31 * MB);
  unsigned short* bqc = (unsigned short*)(ws + 33 * MB);        // 2 KB each
  unsigned short* bkc = (unsigned short*)(ws + 33 * MB + 4096);
  unsigned short* bvc = (unsigned short*)(ws + 33 * MB + 8192);
  unsigned short* boc = (unsigned short*)(ws + 33 * MB + 12288);
  unsigned short* Qb  = (unsigned short*)(ws + 35 * MB);        // 8 MB each
  unsigned short* Kb  = (unsigned short*)(ws + 43 * MB);
  unsigned short* Vb  = (unsigned short*)(ws + 51 * MB);
  unsigned short* Ab  = (unsigned short*)(ws + 59 * MB);

  const long nQKV = (long)MROWS * DMODEL;   // 4194304
  const long nW   = (long)DMODEL * DMODEL;  // 1048576
  convert_f2b<<<1024, 256, 0, stream>>>((const float*)d_in[0], Qc, nQKV / 8);
  convert_f2b<<<1024, 256, 0, stream>>>((const float*)d_in[1], Kc, nQKV / 8);
  convert_f2b<<<1024, 256, 0, stream>>>((const float*)d_in[2], Vc, nQKV / 8);
  convert_f2b<<<256, 256, 0, stream>>>((const float*)d_in[4], Wqc, nW / 8);
  convert_f2b<<<256, 256, 0, stream>>>((const float*)d_in[6], Wkc, nW / 8);
  convert_f2b<<<256, 256, 0, stream>>>((const float*)d_in[8], Wvc, nW / 8);
  convert_f2b<<<256, 256, 0, stream>>>((const float*)d_in[10], Woc, nW / 8);
  convert_f2b<<<1, 128, 0, stream>>>((const float*)d_in[5], bqc, DMODEL / 8);
  convert_f2b<<<1, 128, 0, stream>>>((const float*)d_in[7], bkc, DMODEL / 8);
  convert_f2b<<<1, 128, 0, stream>>>((const float*)d_in[9], bvc, DMODEL / 8);
  convert_f2b<<<1, 128, 0, stream>>>((const float*)d_in[11], boc, DMODEL / 8);

  const int nwords = BATCH * SEQ * (SEQ / 64);  // 131072
  pack_mask<<<512, 256, 0, stream>>>(maskp, pm, nwords);

  gemm_bt<<<256, 256, 0, stream>>>(Qc, Wqc, bqc, Qb, 1);
  gemm_bt<<<256, 256, 0, stream>>>(Kc, Wkc, bkc, Kb, 1);
  gemm_bt<<<256, 256, 0, stream>>>(Vc, Wvc, bvc, Vb, 1);

  attn<<<BATCH * NH * (SEQ / 64), 256, 0, stream>>>(Qb, Kb, Vb, pm, Ab);

  gemm_bt<<<256, 256, 0, stream>>>(Ab, Woc, boc, out, 0);
}

// Round 8
// 225.725 us; speedup vs baseline: 22.6305x; 1.3943x over previous
//
#include <hip/hip_runtime.h>
#include <hip/hip_bf16.h>

#define NH 16
#define DK 64
#define SEQ 2048
#define DMODEL 1024
#define BATCH 2
#define MROWS (BATCH * SEQ) /* 4096 */

using bf16x8 = __attribute__((ext_vector_type(8))) short;
using f32x4  = __attribute__((ext_vector_type(4))) float;

#define NEGI (-1e30f)

static __device__ __forceinline__ unsigned short f2bf(float x) {
  unsigned u = __builtin_bit_cast(unsigned, x);
  u += 0x7fffu + ((u >> 16) & 1u);   // RNE
  return (unsigned short)(u >> 16);
}
static __device__ __forceinline__ float bf2f(unsigned short h) {
  unsigned u = ((unsigned)h) << 16;
  return __builtin_bit_cast(float, u);
}

// ------------------------------------------------- converts (f32 -> bf16)
__global__ __launch_bounds__(256) void convert3(const float* __restrict__ s0,
                                                const float* __restrict__ s1,
                                                const float* __restrict__ s2,
                                                unsigned short* __restrict__ d0,
                                                unsigned short* __restrict__ d1,
                                                unsigned short* __restrict__ d2,
                                                long n8, int blkseg) {
  int seg = blockIdx.x / blkseg;
  int ib  = blockIdx.x % blkseg;
  const float* s = seg == 0 ? s0 : (seg == 1 ? s1 : s2);
  unsigned short* d = seg == 0 ? d0 : (seg == 1 ? d1 : d2);
  long i0 = (long)ib * blockDim.x + threadIdx.x;
  long stride = (long)blkseg * blockDim.x;
  for (long i = i0; i < n8; i += stride) {
    const float* p = s + i * 8;
    float4 a = *(const float4*)(p);
    float4 b = *(const float4*)(p + 4);
    bf16x8 v;
    v[0] = (short)f2bf(a.x); v[1] = (short)f2bf(a.y);
    v[2] = (short)f2bf(a.z); v[3] = (short)f2bf(a.w);
    v[4] = (short)f2bf(b.x); v[5] = (short)f2bf(b.y);
    v[6] = (short)f2bf(b.z); v[7] = (short)f2bf(b.w);
    *(bf16x8*)(d + i * 8) = v;
  }
}
__global__ __launch_bounds__(256) void convert4(const float* __restrict__ s0,
                                                const float* __restrict__ s1,
                                                const float* __restrict__ s2,
                                                const float* __restrict__ s3,
                                                unsigned short* __restrict__ d0,
                                                unsigned short* __restrict__ d1,
                                                unsigned short* __restrict__ d2,
                                                unsigned short* __restrict__ d3,
                                                long n8, int blkseg) {
  int seg = blockIdx.x / blkseg;
  int ib  = blockIdx.x % blkseg;
  const float* s = seg == 0 ? s0 : (seg == 1 ? s1 : (seg == 2 ? s2 : s3));
  unsigned short* d = seg == 0 ? d0 : (seg == 1 ? d1 : (seg == 2 ? d2 : d3));
  long i0 = (long)ib * blockDim.x + threadIdx.x;
  long stride = (long)blkseg * blockDim.x;
  for (long i = i0; i < n8; i += stride) {
    const float* p = s + i * 8;
    float4 a = *(const float4*)(p);
    float4 b = *(const float4*)(p + 4);
    bf16x8 v;
    v[0] = (short)f2bf(a.x); v[1] = (short)f2bf(a.y);
    v[2] = (short)f2bf(a.z); v[3] = (short)f2bf(a.w);
    v[4] = (short)f2bf(b.x); v[5] = (short)f2bf(b.y);
    v[6] = (short)f2bf(b.z); v[7] = (short)f2bf(b.w);
    *(bf16x8*)(d + i * 8) = v;
  }
}

// ---------------------------------------------------------------- pack mask
__global__ __launch_bounds__(256) void pack_mask(const int* __restrict__ mask,
                                                 unsigned long long* __restrict__ pm,
                                                 int nwords) {
  int wid  = (blockIdx.x * blockDim.x + threadIdx.x) >> 6;
  int lane = threadIdx.x & 63;
  int nw   = (gridDim.x * blockDim.x) >> 6;
  for (int w = wid; w < nwords; w += nw) {
    int v = mask[(long)w * 64 + lane];
    unsigned long long b = __ballot(v != 0);
    if (lane == 0) pm[w] = b;
  }
}

// ---------------------------------------------------------------- GEMM core
// C = A @ W^T + bias. r6-proven vector staging (padded LDS, 2 barriers/K-step).
// mode 1: scatter bf16 to [B,H,S,dk].  mode 0: row-major f32.
#define BK 32
#define LDA_ 40

static __device__ __forceinline__ void gemm_body(const unsigned short* __restrict__ A,
                                                 const unsigned short* __restrict__ W,
                                                 const unsigned short* __restrict__ bias,
                                                 void* __restrict__ Cv,
                                                 int mode, int bid,
                                                 unsigned short* Al, unsigned short* Bl) {
  const int t    = threadIdx.x;
  const int lane = t & 63;
  const int w    = t >> 6;
  const int wm   = w >> 1, wn = w & 1;
  const int g    = lane >> 4, lr = lane & 15;
  const int nb   = bid & 7;
  const int mb   = bid >> 3;
  const long Abase = (long)mb * 128 * 1024;
  const long Wbase = (long)nb * 128 * 1024;

  f32x4 acc[4][4] = {};

  for (int kt = 0; kt < 1024; kt += BK) {
    __syncthreads();
#pragma unroll
    for (int q = 0; q < 2; ++q) {   // stage 128x32 of A and W (vector loads)
      int id  = q * 256 + t;
      int row = id >> 2;
      int c8  = (id & 3) << 3;
      bf16x8 va = *(const bf16x8*)(A + Abase + (long)row * 1024 + kt + c8);
      bf16x8 vb = *(const bf16x8*)(W + Wbase + (long)row * 1024 + kt + c8);
      *(bf16x8*)(&Al[row * LDA_ + c8]) = va;
      *(bf16x8*)(&Bl[row * LDA_ + c8]) = vb;
    }
    __syncthreads();
    bf16x8 af[4], bfr[4];
#pragma unroll
    for (int i = 0; i < 4; ++i) {
      af[i]  = *(const bf16x8*)(&Al[(wm * 64 + i * 16 + lr) * LDA_ + g * 8]);
      bfr[i] = *(const bf16x8*)(&Bl[(wn * 64 + i * 16 + lr) * LDA_ + g * 8]);
    }
#pragma unroll
    for (int i = 0; i < 4; ++i)
#pragma unroll
      for (int j = 0; j < 4; ++j)
        acc[i][j] = __builtin_amdgcn_mfma_f32_16x16x32_bf16(af[i], bfr[j], acc[i][j], 0, 0, 0);
  }

#pragma unroll
  for (int j = 0; j < 4; ++j) {
    int n = nb * 128 + wn * 64 + j * 16 + lr;
    float bv = bf2f(bias[n]);
#pragma unroll
    for (int i = 0; i < 4; ++i) {
#pragma unroll
      for (int r = 0; r < 4; ++r) {
        int m = mb * 128 + wm * 64 + i * 16 + g * 4 + r;
        float v = acc[i][j][r] + bv;
        if (mode == 1) {
          int b = m >> 11, s = m & (SEQ - 1);
          int h = n >> 6, d = n & (DK - 1);
          ((unsigned short*)Cv)[(((long)(b * NH + h) * SEQ + s) << 6) + d] = f2bf(v);
        } else {
          ((float*)Cv)[(long)m * DMODEL + n] = v;
        }
      }
    }
  }
}

// merged Q/K/V projection: 768 blocks, which = blockIdx.x >> 8
__global__ __launch_bounds__(256) void qkv_proj(const unsigned short* __restrict__ Aq,
                                                const unsigned short* __restrict__ Ak,
                                                const unsigned short* __restrict__ Av,
                                                const unsigned short* __restrict__ Wq,
                                                const unsigned short* __restrict__ Wk,
                                                const unsigned short* __restrict__ Wv,
                                                const unsigned short* __restrict__ bq,
                                                const unsigned short* __restrict__ bk,
                                                const unsigned short* __restrict__ bv,
                                                unsigned short* __restrict__ Cq,
                                                unsigned short* __restrict__ Ck,
                                                unsigned short* __restrict__ Cv) {
  __shared__ unsigned short Al[128 * LDA_];
  __shared__ unsigned short Bl[128 * LDA_];
  int which = blockIdx.x >> 8;
  int bid   = blockIdx.x & 255;
  const unsigned short* A = which == 0 ? Aq : (which == 1 ? Ak : Av);
  const unsigned short* W = which == 0 ? Wq : (which == 1 ? Wk : Wv);
  const unsigned short* b = which == 0 ? bq : (which == 1 ? bk : bv);
  unsigned short* C = which == 0 ? Cq : (which == 1 ? Ck : Cv);
  gemm_body(A, W, b, C, 1, bid, Al, Bl);
}

__global__ __launch_bounds__(256) void gemm_out(const unsigned short* __restrict__ A,
                                                const unsigned short* __restrict__ W,
                                                const unsigned short* __restrict__ bias,
                                                float* __restrict__ C) {
  __shared__ unsigned short Al[128 * LDA_];
  __shared__ unsigned short Bl[128 * LDA_];
  gemm_body(A, W, bias, C, 0, blockIdx.x, Al, Bl);
}

// ---------------------------------------------------------------- attention
// Swapped QK^T: s[c][r] = S[kv=c*16+g*4+r][q=q0+lr]; per-lane softmax (q=lr)
// + defer-max (THR=5). Barrier structure identical to replay-proven r6.
#define KVB 64
#define LD 72

__global__ __launch_bounds__(256) void attn(const unsigned short* __restrict__ Q,
                                            const unsigned short* __restrict__ K,
                                            const unsigned short* __restrict__ V,
                                            const unsigned long long* __restrict__ pm,
                                            unsigned short* __restrict__ O) {
  __shared__ unsigned short Kl[KVB * LD];
  __shared__ unsigned short Vt[DK * LD];
  __shared__ unsigned short Pl[4][16 * LD];
  const int t    = threadIdx.x;
  const int lane = t & 63;
  const int w    = t >> 6;
  const int g    = lane >> 4, lr = lane & 15;
  const int qb   = blockIdx.x & 31;
  const int bh   = blockIdx.x >> 5;
  const int b    = bh >> 4, h = bh & 15;
  const long base = (long)bh * SEQ * DK;
  const int q0   = qb * 64 + w * 16;

  bf16x8 qf[2];
  {
    const unsigned short* qp = Q + base + (long)(q0 + lr) * DK;
    qf[0] = *(const bf16x8*)(qp + g * 8);
    qf[1] = *(const bf16x8*)(qp + 32 + g * 8);
  }
  float mrun = NEGI, lrun = 0.f;   // per-lane: q = q0 + lr
  f32x4 o[4] = {};
  const float scale = 0.125f;
  const unsigned long long* pmrow = pm + ((long)b * SEQ + q0 + lr) * 32;

  for (int kt = 0; kt < SEQ / KVB; ++kt) {
    const int kvbase = kt * KVB;
    __syncthreads();
#pragma unroll
    for (int p = 0; p < 2; ++p) {
      int id  = p * 256 + t;
      int row = id >> 3;
      int c8  = (id & 7) << 3;
      bf16x8 kv8 = *(const bf16x8*)(K + base + (long)(kvbase + row) * DK + c8);
      *(bf16x8*)(&Kl[row * LD + c8]) = kv8;
    }
#pragma unroll
    for (int p = 0; p < 2; ++p) {
      int d0 = (w + p * 4) * 8;
      bf16x8 vv = *(const bf16x8*)(V + base + (long)(kvbase + lane) * DK + d0);
#pragma unroll
      for (int e = 0; e < 8; ++e) Vt[(d0 + e) * LD + lane] = (unsigned short)vv[e];
    }
    __syncthreads();

    const unsigned long long mw = pmrow[kt];

    // swapped scores: A=K rows, B=Q rows -> C[kv][q]
    f32x4 sc[4];
#pragma unroll
    for (int c = 0; c < 4; ++c) {
      f32x4 a = {};
      bf16x8 kf0 = *(const bf16x8*)(&Kl[(c * 16 + lr) * LD + g * 8]);
      bf16x8 kf1 = *(const bf16x8*)(&Kl[(c * 16 + lr) * LD + 32 + g * 8]);
      a = __builtin_amdgcn_mfma_f32_16x16x32_bf16(kf0, qf[0], a, 0, 0, 0);
      a = __builtin_amdgcn_mfma_f32_16x16x32_bf16(kf1, qf[1], a, 0, 0, 0);
      sc[c] = a;
    }
    float s[4][4];
    float mt = NEGI;
#pragma unroll
    for (int c = 0; c < 4; ++c)
#pragma unroll
      for (int r = 0; r < 4; ++r) {
        int kvi = c * 16 + g * 4 + r;
        float v = ((mw >> kvi) & 1ull) ? sc[c][r] * scale : -1e9f;
        s[c][r] = v;
        mt = fmaxf(mt, v);
      }
    mt = fmaxf(mt, __shfl_xor(mt, 16, 64));
    mt = fmaxf(mt, __shfl_xor(mt, 32, 64));

    int need = __any(mt > mrun + 5.0f);   // defer-max (T13)
    float mn = mrun, corr = 1.0f;
    if (need) { mn = fmaxf(mrun, mt); corr = __expf(mrun - mn); mrun = mn; }

    float pf[4][4];
    float rs = 0.f;
#pragma unroll
    for (int c = 0; c < 4; ++c)
#pragma unroll
      for (int r = 0; r < 4; ++r) {
        float p_ = __expf(s[c][r] - mn);
        pf[c][r] = p_;
        rs += p_;
      }
    rs += __shfl_xor(rs, 16, 64);
    rs += __shfl_xor(rs, 32, 64);

    if (need) {
      lrun = lrun * corr + rs;
#pragma unroll
      for (int r = 0; r < 4; ++r) {
        float cq = __shfl(corr, (lane >> 4) * 4 + r, 64);  // corr of q-row g*4+r
#pragma unroll
        for (int dt = 0; dt < 4; ++dt) o[dt][r] *= cq;
      }
    } else {
      lrun += rs;
    }

    // P store (A-fragment layout): row q=lr, kv cols; b64 stores
    unsigned short* P = &Pl[w][0];
#pragma unroll
    for (int c = 0; c < 4; ++c) {
      uint2 pk;
      pk.x = (unsigned)f2bf(pf[c][0]) | ((unsigned)f2bf(pf[c][1]) << 16);
      pk.y = (unsigned)f2bf(pf[c][2]) | ((unsigned)f2bf(pf[c][3]) << 16);
      *(uint2*)(&P[lr * LD + c * 16 + g * 4]) = pk;
    }
    __syncthreads();   // fence stores vs vector re-reads (r6-proven)
#pragma unroll
    for (int c32 = 0; c32 < 2; ++c32) {
      bf16x8 pfrag = *(const bf16x8*)(&P[lr * LD + c32 * 32 + g * 8]);
#pragma unroll
      for (int dt = 0; dt < 4; ++dt) {
        bf16x8 vf = *(const bf16x8*)(&Vt[(dt * 16 + lr) * LD + c32 * 32 + g * 8]);
        o[dt] = __builtin_amdgcn_mfma_f32_16x16x32_bf16(pfrag, vf, o[dt], 0, 0, 0);
      }
    }
  }
  float inv = 1.0f / lrun;
#pragma unroll
  for (int r = 0; r < 4; ++r) {
    float iq = __shfl(inv, (lane >> 4) * 4 + r, 64);
    int q = q0 + g * 4 + r;
    unsigned short* op = O + ((long)(b * SEQ + q) * DMODEL) + h * DK;
#pragma unroll
    for (int dt = 0; dt < 4; ++dt) op[dt * 16 + lr] = f2bf(o[dt][r] * iq);
  }
}

// ---------------------------------------------------------------- launch
extern "C" void kernel_launch(void* const* d_in, const int* in_sizes, int n_in,
                              void* d_out, int out_size, void* d_ws, size_t ws_size,
                              hipStream_t stream) {
  const int* maskp = (const int*)d_in[3];
  float* out = (float*)d_out;

  char* ws = (char*)d_ws;
  const long MB = 1 << 20;
  unsigned long long* pm = (unsigned long long*)ws;             // 1 MB
  unsigned short* Qc  = (unsigned short*)(ws + 1 * MB);         // 8 MB each
  unsigned short* Kc  = (unsigned short*)(ws + 9 * MB);
  unsigned short* Vc  = (unsigned short*)(ws + 17 * MB);
  unsigned short* Wqc = (unsigned short*)(ws + 25 * MB);        // 2 MB each
  unsigned short* Wkc = (unsigned short*)(ws + 27 * MB);
  unsigned short* Wvc = (unsigned short*)(ws + 29 * MB);
  unsigned short* Woc = (unsigned short*)(ws + 31 * MB);
  unsigned short* bqc = (unsigned short*)(ws + 33 * MB);        // 2 KB each
  unsigned short* bkc = (unsigned short*)(ws + 33 * MB + 4096);
  unsigned short* bvc = (unsigned short*)(ws + 33 * MB + 8192);
  unsigned short* boc = (unsigned short*)(ws + 33 * MB + 12288);
  unsigned short* Qb  = (unsigned short*)(ws + 35 * MB);        // 8 MB each
  unsigned short* Kb  = (unsigned short*)(ws + 43 * MB);
  unsigned short* Vb  = (unsigned short*)(ws + 51 * MB);
  unsigned short* Ab  = (unsigned short*)(ws + 59 * MB);

  const long nQKV8 = (long)MROWS * DMODEL / 8;   // 524288
  const long nW8   = (long)DMODEL * DMODEL / 8;  // 131072
  convert3<<<1536, 256, 0, stream>>>((const float*)d_in[0], (const float*)d_in[1],
                                     (const float*)d_in[2], Qc, Kc, Vc, nQKV8, 512);
  convert4<<<512, 256, 0, stream>>>((const float*)d_in[4], (const float*)d_in[6],
                                    (const float*)d_in[8], (const float*)d_in[10],
                                    Wqc, Wkc, Wvc, Woc, nW8, 128);
  convert4<<<4, 256, 0, stream>>>((const float*)d_in[5], (const float*)d_in[7],
                                  (const float*)d_in[9], (const float*)d_in[11],
                                  bqc, bkc, bvc, boc, DMODEL / 8, 1);

  const int nwords = BATCH * SEQ * (SEQ / 64);  // 131072
  pack_mask<<<512, 256, 0, stream>>>(maskp, pm, nwords);

  qkv_proj<<<768, 256, 0, stream>>>(Qc, Kc, Vc, Wqc, Wkc, Wvc,
                                    bqc, bkc, bvc, Qb, Kb, Vb);

  attn<<<BATCH * NH * (SEQ / 64), 256, 0, stream>>>(Qb, Kb, Vb, pm, Ab);

  gemm_out<<<256, 256, 0, stream>>>(Ab, Woc, boc, out);
}

// Round 9
// 217.445 us; speedup vs baseline: 23.4922x; 1.0381x over previous
//
#include <hip/hip_runtime.h>
#include <hip/hip_bf16.h>

#define NH 16
#define DK 64
#define SEQ 2048
#define DMODEL 1024
#define BATCH 2
#define MROWS (BATCH * SEQ) /* 4096 */

using bf16x8 = __attribute__((ext_vector_type(8))) short;
using f32x4  = __attribute__((ext_vector_type(4))) float;

#define NEGI (-1e30f)
#define QSCALE 0.18033688f  /* 0.125 * log2(e): folds 1/sqrt(dk) and exp->exp2 */

static __device__ __forceinline__ unsigned short f2bf(float x) {
  unsigned u = __builtin_bit_cast(unsigned, x);
  u += 0x7fffu + ((u >> 16) & 1u);   // RNE
  return (unsigned short)(u >> 16);
}
static __device__ __forceinline__ float bf2f(unsigned short h) {
  unsigned u = ((unsigned)h) << 16;
  return __builtin_bit_cast(float, u);
}
// packed f32x2 -> bf16x2 (lo = a, hi = b), single VALU inst
static __device__ __forceinline__ unsigned cvtpk(float a, float b) {
  unsigned r;
  asm("v_cvt_pk_bf16_f32 %0, %1, %2" : "=v"(r) : "v"(a), "v"(b));
  return r;
}

// ------------------------------------------------- converts (f32 -> bf16)
__global__ __launch_bounds__(256) void convert3(const float* __restrict__ s0,
                                                const float* __restrict__ s1,
                                                const float* __restrict__ s2,
                                                unsigned short* __restrict__ d0,
                                                unsigned short* __restrict__ d1,
                                                unsigned short* __restrict__ d2,
                                                long n8, int blkseg) {
  int seg = blockIdx.x / blkseg;
  int ib  = blockIdx.x % blkseg;
  const float* s = seg == 0 ? s0 : (seg == 1 ? s1 : s2);
  unsigned short* d = seg == 0 ? d0 : (seg == 1 ? d1 : d2);
  long i0 = (long)ib * blockDim.x + threadIdx.x;
  long stride = (long)blkseg * blockDim.x;
  for (long i = i0; i < n8; i += stride) {
    const float* p = s + i * 8;
    float4 a = *(const float4*)(p);
    float4 b = *(const float4*)(p + 4);
    bf16x8 v;
    v[0] = (short)f2bf(a.x); v[1] = (short)f2bf(a.y);
    v[2] = (short)f2bf(a.z); v[3] = (short)f2bf(a.w);
    v[4] = (short)f2bf(b.x); v[5] = (short)f2bf(b.y);
    v[6] = (short)f2bf(b.z); v[7] = (short)f2bf(b.w);
    *(bf16x8*)(d + i * 8) = v;
  }
}
__global__ __launch_bounds__(256) void convert4(const float* __restrict__ s0,
                                                const float* __restrict__ s1,
                                                const float* __restrict__ s2,
                                                const float* __restrict__ s3,
                                                unsigned short* __restrict__ d0,
                                                unsigned short* __restrict__ d1,
                                                unsigned short* __restrict__ d2,
                                                unsigned short* __restrict__ d3,
                                                long n8, int blkseg) {
  int seg = blockIdx.x / blkseg;
  int ib  = blockIdx.x % blkseg;
  const float* s = seg == 0 ? s0 : (seg == 1 ? s1 : (seg == 2 ? s2 : s3));
  unsigned short* d = seg == 0 ? d0 : (seg == 1 ? d1 : (seg == 2 ? d2 : d3));
  long i0 = (long)ib * blockDim.x + threadIdx.x;
  long stride = (long)blkseg * blockDim.x;
  for (long i = i0; i < n8; i += stride) {
    const float* p = s + i * 8;
    float4 a = *(const float4*)(p);
    float4 b = *(const float4*)(p + 4);
    bf16x8 v;
    v[0] = (short)f2bf(a.x); v[1] = (short)f2bf(a.y);
    v[2] = (short)f2bf(a.z); v[3] = (short)f2bf(a.w);
    v[4] = (short)f2bf(b.x); v[5] = (short)f2bf(b.y);
    v[6] = (short)f2bf(b.z); v[7] = (short)f2bf(b.w);
    *(bf16x8*)(d + i * 8) = v;
  }
}

// ---------------------------------------------------------------- pack mask
__global__ __launch_bounds__(256) void pack_mask(const int* __restrict__ mask,
                                                 unsigned long long* __restrict__ pm,
                                                 int nwords) {
  int wid  = (blockIdx.x * blockDim.x + threadIdx.x) >> 6;
  int lane = threadIdx.x & 63;
  int nw   = (gridDim.x * blockDim.x) >> 6;
  for (int w = wid; w < nwords; w += nw) {
    int v = mask[(long)w * 64 + lane];
    unsigned long long b = __ballot(v != 0);
    if (lane == 0) pm[w] = b;
  }
}

// ---------------------------------------------------------------- GEMM core
// C = (A @ W^T + bias) * cscale.  r8-proven vector staging, 2 barriers/K-step.
// mode 0: row-major f32.  mode 1: bf16 scatter [B,H,S,dk].
// mode 2: bf16 scatter-transposed [B,H,dk,S] with packed 8B stores.
#define BK 32
#define LDA_ 40

static __device__ __forceinline__ void gemm_body(const unsigned short* __restrict__ A,
                                                 const unsigned short* __restrict__ W,
                                                 const unsigned short* __restrict__ bias,
                                                 void* __restrict__ Cv,
                                                 int mode, float cscale, int bid,
                                                 unsigned short* Al, unsigned short* Bl) {
  const int t    = threadIdx.x;
  const int lane = t & 63;
  const int w    = t >> 6;
  const int wm   = w >> 1, wn = w & 1;
  const int g    = lane >> 4, lr = lane & 15;
  const int nb   = bid & 7;
  const int mb   = bid >> 3;
  const long Abase = (long)mb * 128 * 1024;
  const long Wbase = (long)nb * 128 * 1024;

  f32x4 acc[4][4] = {};

  for (int kt = 0; kt < 1024; kt += BK) {
    __syncthreads();
#pragma unroll
    for (int q = 0; q < 2; ++q) {   // stage 128x32 of A and W (vector loads)
      int id  = q * 256 + t;
      int row = id >> 2;
      int c8  = (id & 3) << 3;
      bf16x8 va = *(const bf16x8*)(A + Abase + (long)row * 1024 + kt + c8);
      bf16x8 vb = *(const bf16x8*)(W + Wbase + (long)row * 1024 + kt + c8);
      *(bf16x8*)(&Al[row * LDA_ + c8]) = va;
      *(bf16x8*)(&Bl[row * LDA_ + c8]) = vb;
    }
    __syncthreads();
    bf16x8 af[4], bfr[4];
#pragma unroll
    for (int i = 0; i < 4; ++i) {
      af[i]  = *(const bf16x8*)(&Al[(wm * 64 + i * 16 + lr) * LDA_ + g * 8]);
      bfr[i] = *(const bf16x8*)(&Bl[(wn * 64 + i * 16 + lr) * LDA_ + g * 8]);
    }
#pragma unroll
    for (int i = 0; i < 4; ++i)
#pragma unroll
      for (int j = 0; j < 4; ++j)
        acc[i][j] = __builtin_amdgcn_mfma_f32_16x16x32_bf16(af[i], bfr[j], acc[i][j], 0, 0, 0);
  }

#pragma unroll
  for (int j = 0; j < 4; ++j) {
    int n = nb * 128 + wn * 64 + j * 16 + lr;
    float bv = bf2f(bias[n]);
#pragma unroll
    for (int i = 0; i < 4; ++i) {
      int m0 = mb * 128 + wm * 64 + i * 16 + g * 4;
      float v0 = (acc[i][j][0] + bv) * cscale;
      float v1 = (acc[i][j][1] + bv) * cscale;
      float v2 = (acc[i][j][2] + bv) * cscale;
      float v3 = (acc[i][j][3] + bv) * cscale;
      if (mode == 2) {            // V^T: [B,H,dk,S]; 4 consecutive s -> 8B store
        int b = m0 >> 11, s0 = m0 & (SEQ - 1);
        int h = n >> 6, d = n & (DK - 1);
        uint2 pk;
        pk.x = (unsigned)f2bf(v0) | ((unsigned)f2bf(v1) << 16);
        pk.y = (unsigned)f2bf(v2) | ((unsigned)f2bf(v3) << 16);
        *(uint2*)(&((unsigned short*)Cv)[((long)(b * NH + h) * DK + d) * SEQ + s0]) = pk;
      } else if (mode == 1) {     // [B,H,S,dk]
        int b = m0 >> 11, s0 = m0 & (SEQ - 1);
        int h = n >> 6, d = n & (DK - 1);
        unsigned short* p = &((unsigned short*)Cv)[(((long)(b * NH + h) * SEQ + s0) << 6) + d];
        p[0] = f2bf(v0); p[64] = f2bf(v1); p[128] = f2bf(v2); p[192] = f2bf(v3);
      } else {                    // row-major f32
        float* p = &((float*)Cv)[(long)m0 * DMODEL + n];
        p[0] = v0; p[DMODEL] = v1; p[2 * DMODEL] = v2; p[3 * DMODEL] = v3;
      }
    }
  }
}

// merged Q/K/V projection: 768 blocks, which = blockIdx.x >> 8
// Q: mode 1 scaled by QSCALE; K: mode 1; V: mode 2 (transposed layout)
__global__ __launch_bounds__(256) void qkv_proj(const unsigned short* __restrict__ Aq,
                                                const unsigned short* __restrict__ Ak,
                                                const unsigned short* __restrict__ Av,
                                                const unsigned short* __restrict__ Wq,
                                                const unsigned short* __restrict__ Wk,
                                                const unsigned short* __restrict__ Wv,
                                                const unsigned short* __restrict__ bq,
                                                const unsigned short* __restrict__ bk,
                                                const unsigned short* __restrict__ bv,
                                                unsigned short* __restrict__ Cq,
                                                unsigned short* __restrict__ Ck,
                                                unsigned short* __restrict__ Cv) {
  __shared__ unsigned short Al[128 * LDA_];
  __shared__ unsigned short Bl[128 * LDA_];
  int which = blockIdx.x >> 8;
  int bid   = blockIdx.x & 255;
  const unsigned short* A = which == 0 ? Aq : (which == 1 ? Ak : Av);
  const unsigned short* W = which == 0 ? Wq : (which == 1 ? Wk : Wv);
  const unsigned short* b = which == 0 ? bq : (which == 1 ? bk : bv);
  unsigned short* C = which == 0 ? Cq : (which == 1 ? Ck : Cv);
  int   mode  = which == 2 ? 2 : 1;
  float scale = which == 0 ? QSCALE : 1.0f;
  gemm_body(A, W, b, C, mode, scale, bid, Al, Bl);
}

__global__ __launch_bounds__(256) void gemm_out(const unsigned short* __restrict__ A,
                                                const unsigned short* __restrict__ W,
                                                const unsigned short* __restrict__ bias,
                                                float* __restrict__ C) {
  __shared__ unsigned short Al[128 * LDA_];
  __shared__ unsigned short Bl[128 * LDA_];
  gemm_body(A, W, bias, C, 0, 1.0f, blockIdx.x, Al, Bl);
}

// ---------------------------------------------------------------- attention
// Q [B,H,S,64] (pre-scaled by QSCALE), K [B,H,S,64], VT [B,H,64,S] bf16.
// Swapped QK^T; per-lane log2-domain softmax + defer-max; V staged as vector
// copies (no transpose). Barrier skeleton identical to replay-proven r8.
#define KVB 64
#define LD 72

__global__ __launch_bounds__(256) void attn(const unsigned short* __restrict__ Q,
                                            const unsigned short* __restrict__ K,
                                            const unsigned short* __restrict__ VT,
                                            const unsigned long long* __restrict__ pm,
                                            unsigned short* __restrict__ O) {
  __shared__ unsigned short Kl[KVB * LD];
  __shared__ unsigned short Vt[DK * LD];       // Vt[d][kv]
  __shared__ unsigned short Pl[4][16 * LD];
  const int t    = threadIdx.x;
  const int lane = t & 63;
  const int w    = t >> 6;
  const int g    = lane >> 4, lr = lane & 15;
  const int qb   = blockIdx.x & 31;
  const int bh   = blockIdx.x >> 5;
  const int b    = bh >> 4, h = bh & 15;
  const long base = (long)bh * SEQ * DK;       // same flat size for K and VT
  const int q0   = qb * 64 + w * 16;

  bf16x8 qf[2];
  {
    const unsigned short* qp = Q + base + (long)(q0 + lr) * DK;
    qf[0] = *(const bf16x8*)(qp + g * 8);
    qf[1] = *(const bf16x8*)(qp + 32 + g * 8);
  }
  float mrun = NEGI, lrun = 0.f;   // log2-domain, per-lane (q = q0 + lr)
  f32x4 o[4] = {};
  const unsigned long long* pmrow = pm + ((long)b * SEQ + q0 + lr) * 32;

  for (int kt = 0; kt < SEQ / KVB; ++kt) {
    const int kvbase = kt * KVB;
    __syncthreads();
    // stage K rows [kv][64] — b128 loads/stores
#pragma unroll
    for (int p = 0; p < 2; ++p) {
      int id  = p * 256 + t;
      int row = id >> 3;
      int c8  = (id & 7) << 3;
      bf16x8 kv8 = *(const bf16x8*)(K + base + (long)(kvbase + row) * DK + c8);
      *(bf16x8*)(&Kl[row * LD + c8]) = kv8;
    }
    // stage V^T rows [d][kv-block] — b128 copies, no transpose needed
#pragma unroll
    for (int p = 0; p < 2; ++p) {
      int id  = p * 256 + t;
      int row = id >> 3;                    // d = 0..63
      int c8  = (id & 7) << 3;              // kv within tile
      bf16x8 vv = *(const bf16x8*)(VT + base + (long)row * SEQ + kvbase + c8);
      *(bf16x8*)(&Vt[row * LD + c8]) = vv;
    }
    __syncthreads();

    const unsigned long long mw = pmrow[kt];

    // swapped scores: C[kv][q];  Q pre-scaled so sc is in log2 units
    f32x4 sc[4];
#pragma unroll
    for (int c = 0; c < 4; ++c) {
      f32x4 a = {};
      bf16x8 kf0 = *(const bf16x8*)(&Kl[(c * 16 + lr) * LD + g * 8]);
      bf16x8 kf1 = *(const bf16x8*)(&Kl[(c * 16 + lr) * LD + 32 + g * 8]);
      a = __builtin_amdgcn_mfma_f32_16x16x32_bf16(kf0, qf[0], a, 0, 0, 0);
      a = __builtin_amdgcn_mfma_f32_16x16x32_bf16(kf1, qf[1], a, 0, 0, 0);
      sc[c] = a;
    }
    float s[4][4];
    float mt = NEGI;
#pragma unroll
    for (int c = 0; c < 4; ++c)
#pragma unroll
      for (int r = 0; r < 4; ++r) {
        int kvi = c * 16 + g * 4 + r;
        float v = ((mw >> kvi) & 1ull) ? sc[c][r] : -1e9f;
        s[c][r] = v;
        mt = fmaxf(mt, v);
      }
    mt = fmaxf(mt, __shfl_xor(mt, 16, 64));
    mt = fmaxf(mt, __shfl_xor(mt, 32, 64));

    int need = __any(mt > mrun + 5.0f);   // defer-max (T13), log2 units
    float mn = mrun, corr = 1.0f;
    if (need) { mn = fmaxf(mrun, mt); corr = __builtin_amdgcn_exp2f(mrun - mn); mrun = mn; }

    float pf[4][4];
    float rs = 0.f;
#pragma unroll
    for (int c = 0; c < 4; ++c)
#pragma unroll
      for (int r = 0; r < 4; ++r) {
        float p_ = __builtin_amdgcn_exp2f(s[c][r] - mn);
        pf[c][r] = p_;
        rs += p_;
      }
    rs += __shfl_xor(rs, 16, 64);
    rs += __shfl_xor(rs, 32, 64);

    if (need) {
      lrun = lrun * corr + rs;
#pragma unroll
      for (int r = 0; r < 4; ++r) {
        float cq = __shfl(corr, (lane >> 4) * 4 + r, 64);  // corr of q-row g*4+r
#pragma unroll
        for (int dt = 0; dt < 4; ++dt) o[dt][r] *= cq;
      }
    } else {
      lrun += rs;
    }

    // P store (A-fragment layout): row q=lr, kv cols; cvt_pk + b64 stores
    unsigned short* P = &Pl[w][0];
#pragma unroll
    for (int c = 0; c < 4; ++c) {
      uint2 pk;
      pk.x = cvtpk(pf[c][0], pf[c][1]);
      pk.y = cvtpk(pf[c][2], pf[c][3]);
      *(uint2*)(&P[lr * LD + c * 16 + g * 4]) = pk;
    }
    __syncthreads();   // fence stores vs vector re-reads (r8-proven)
#pragma unroll
    for (int c32 = 0; c32 < 2; ++c32) {
      bf16x8 pfrag = *(const bf16x8*)(&P[lr * LD + c32 * 32 + g * 8]);
#pragma unroll
      for (int dt = 0; dt < 4; ++dt) {
        bf16x8 vf = *(const bf16x8*)(&Vt[(dt * 16 + lr) * LD + c32 * 32 + g * 8]);
        o[dt] = __builtin_amdgcn_mfma_f32_16x16x32_bf16(pfrag, vf, o[dt], 0, 0, 0);
      }
    }
  }
  float inv = 1.0f / lrun;
#pragma unroll
  for (int r = 0; r < 4; ++r) {
    float iq = __shfl(inv, (lane >> 4) * 4 + r, 64);
    int q = q0 + g * 4 + r;
    unsigned short* op = O + ((long)(b * SEQ + q) * DMODEL) + h * DK;
#pragma unroll
    for (int dt = 0; dt < 4; ++dt) op[dt * 16 + lr] = f2bf(o[dt][r] * iq);
  }
}

// ---------------------------------------------------------------- launch
extern "C" void kernel_launch(void* const* d_in, const int* in_sizes, int n_in,
                              void* d_out, int out_size, void* d_ws, size_t ws_size,
                              hipStream_t stream) {
  const int* maskp = (const int*)d_in[3];
  float* out = (float*)d_out;

  char* ws = (char*)d_ws;
  const long MB = 1 << 20;
  unsigned long long* pm = (unsigned long long*)ws;             // 1 MB
  unsigned short* Qc  = (unsigned short*)(ws + 1 * MB);         // 8 MB each
  unsigned short* Kc  = (unsigned short*)(ws + 9 * MB);
  unsigned short* Vc  = (unsigned short*)(ws + 17 * MB);
  unsigned short* Wqc = (unsigned short*)(ws + 25 * MB);        // 2 MB each
  unsigned short* Wkc = (unsigned short*)(ws + 27 * MB);
  unsigned short* Wvc = (unsigned short*)(ws + 29 * MB);
  unsigned short* Woc = (unsigned short*)(ws + 31 * MB);
  unsigned short* bqc = (unsigned short*)(ws + 33 * MB);        // 2 KB each
  unsigned short* bkc = (unsigned short*)(ws + 33 * MB + 4096);
  unsigned short* bvc = (unsigned short*)(ws + 33 * MB + 8192);
  unsigned short* boc = (unsigned short*)(ws + 33 * MB + 12288);
  unsigned short* Qb  = (unsigned short*)(ws + 35 * MB);        // 8 MB each
  unsigned short* Kb  = (unsigned short*)(ws + 43 * MB);
  unsigned short* Vb  = (unsigned short*)(ws + 51 * MB);        // holds V^T
  unsigned short* Ab  = (unsigned short*)(ws + 59 * MB);

  const long nQKV8 = (long)MROWS * DMODEL / 8;   // 524288
  const long nW8   = (long)DMODEL * DMODEL / 8;  // 131072
  convert3<<<1536, 256, 0, stream>>>((const float*)d_in[0], (const float*)d_in[1],
                                     (const float*)d_in[2], Qc, Kc, Vc, nQKV8, 512);
  convert4<<<512, 256, 0, stream>>>((const float*)d_in[4], (const float*)d_in[6],
                                    (const float*)d_in[8], (const float*)d_in[10],
                                    Wqc, Wkc, Wvc, Woc, nW8, 128);
  convert4<<<4, 256, 0, stream>>>((const float*)d_in[5], (const float*)d_in[7],
                                  (const float*)d_in[9], (const float*)d_in[11],
                                  bqc, bkc, bvc, boc, DMODEL / 8, 1);

  const int nwords = BATCH * SEQ * (SEQ / 64);  // 131072
  pack_mask<<<512, 256, 0, stream>>>(maskp, pm, nwords);

  qkv_proj<<<768, 256, 0, stream>>>(Qc, Kc, Vc, Wqc, Wkc, Wvc,
                                    bqc, bkc, bvc, Qb, Kb, Vb);

  attn<<<BATCH * NH * (SEQ / 64), 256, 0, stream>>>(Qb, Kb, Vb, pm, Ab);

  gemm_out<<<256, 256, 0, stream>>>(Ab, Woc, boc, out);
}

// Round 10
// 213.733 us; speedup vs baseline: 23.9002x; 1.0174x over previous
//
#include <hip/hip_runtime.h>
#include <hip/hip_bf16.h>

#define NH 16
#define DK 64
#define SEQ 2048
#define DMODEL 1024
#define BATCH 2
#define MROWS (BATCH * SEQ) /* 4096 */

using bf16x8 = __attribute__((ext_vector_type(8))) short;
using f32x4  = __attribute__((ext_vector_type(4))) float;

#define NEGI (-1e30f)
#define QSCALE 0.18033688f  /* 0.125 * log2(e): folds 1/sqrt(dk) and exp->exp2 */

static __device__ __forceinline__ unsigned short f2bf(float x) {
  unsigned u = __builtin_bit_cast(unsigned, x);
  u += 0x7fffu + ((u >> 16) & 1u);   // RNE
  return (unsigned short)(u >> 16);
}
static __device__ __forceinline__ float bf2f(unsigned short h) {
  unsigned u = ((unsigned)h) << 16;
  return __builtin_bit_cast(float, u);
}
// packed f32x2 -> bf16x2 (lo = a, hi = b), single VALU inst
static __device__ __forceinline__ unsigned cvtpk(float a, float b) {
  unsigned r;
  asm("v_cvt_pk_bf16_f32 %0, %1, %2" : "=v"(r) : "v"(a), "v"(b));
  return r;
}

// ------------------------------------------------- converts (f32 -> bf16)
__global__ __launch_bounds__(256) void convert3(const float* __restrict__ s0,
                                                const float* __restrict__ s1,
                                                const float* __restrict__ s2,
                                                unsigned short* __restrict__ d0,
                                                unsigned short* __restrict__ d1,
                                                unsigned short* __restrict__ d2,
                                                long n8, int blkseg) {
  int seg = blockIdx.x / blkseg;
  int ib  = blockIdx.x % blkseg;
  const float* s = seg == 0 ? s0 : (seg == 1 ? s1 : s2);
  unsigned short* d = seg == 0 ? d0 : (seg == 1 ? d1 : d2);
  long i0 = (long)ib * blockDim.x + threadIdx.x;
  long stride = (long)blkseg * blockDim.x;
  for (long i = i0; i < n8; i += stride) {
    const float* p = s + i * 8;
    float4 a = *(const float4*)(p);
    float4 b = *(const float4*)(p + 4);
    bf16x8 v;
    v[0] = (short)f2bf(a.x); v[1] = (short)f2bf(a.y);
    v[2] = (short)f2bf(a.z); v[3] = (short)f2bf(a.w);
    v[4] = (short)f2bf(b.x); v[5] = (short)f2bf(b.y);
    v[6] = (short)f2bf(b.z); v[7] = (short)f2bf(b.w);
    *(bf16x8*)(d + i * 8) = v;
  }
}
__global__ __launch_bounds__(256) void convert4(const float* __restrict__ s0,
                                                const float* __restrict__ s1,
                                                const float* __restrict__ s2,
                                                const float* __restrict__ s3,
                                                unsigned short* __restrict__ d0,
                                                unsigned short* __restrict__ d1,
                                                unsigned short* __restrict__ d2,
                                                unsigned short* __restrict__ d3,
                                                long n8, int blkseg) {
  int seg = blockIdx.x / blkseg;
  int ib  = blockIdx.x % blkseg;
  const float* s = seg == 0 ? s0 : (seg == 1 ? s1 : (seg == 2 ? s2 : s3));
  unsigned short* d = seg == 0 ? d0 : (seg == 1 ? d1 : (seg == 2 ? d2 : d3));
  long i0 = (long)ib * blockDim.x + threadIdx.x;
  long stride = (long)blkseg * blockDim.x;
  for (long i = i0; i < n8; i += stride) {
    const float* p = s + i * 8;
    float4 a = *(const float4*)(p);
    float4 b = *(const float4*)(p + 4);
    bf16x8 v;
    v[0] = (short)f2bf(a.x); v[1] = (short)f2bf(a.y);
    v[2] = (short)f2bf(a.z); v[3] = (short)f2bf(a.w);
    v[4] = (short)f2bf(b.x); v[5] = (short)f2bf(b.y);
    v[6] = (short)f2bf(b.z); v[7] = (short)f2bf(b.w);
    *(bf16x8*)(d + i * 8) = v;
  }
}

// ---------------------------------------------------------------- pack mask
__global__ __launch_bounds__(256) void pack_mask(const int* __restrict__ mask,
                                                 unsigned long long* __restrict__ pm,
                                                 int nwords) {
  int wid  = (blockIdx.x * blockDim.x + threadIdx.x) >> 6;
  int lane = threadIdx.x & 63;
  int nw   = (gridDim.x * blockDim.x) >> 6;
  for (int w = wid; w < nwords; w += nw) {
    int v = mask[(long)w * 64 + lane];
    unsigned long long b = __ballot(v != 0);
    if (lane == 0) pm[w] = b;
  }
}

// ---------------------------------------------------------------- GEMM core
// C = (A @ W^T + bias) * cscale.  r8-proven vector staging, 2 barriers/K-step.
// mode 0: row-major f32.  mode 1: bf16 scatter [B,H,S,dk].
// mode 2: bf16 scatter-transposed [B,H,dk,S] with packed 8B stores.
#define BK 32
#define LDA_ 40

static __device__ __forceinline__ void gemm_body(const unsigned short* __restrict__ A,
                                                 const unsigned short* __restrict__ W,
                                                 const unsigned short* __restrict__ bias,
                                                 void* __restrict__ Cv,
                                                 int mode, float cscale, int bid,
                                                 unsigned short* Al, unsigned short* Bl) {
  const int t    = threadIdx.x;
  const int lane = t & 63;
  const int w    = t >> 6;
  const int wm   = w >> 1, wn = w & 1;
  const int g    = lane >> 4, lr = lane & 15;
  const int nb   = bid & 7;
  const int mb   = bid >> 3;
  const long Abase = (long)mb * 128 * 1024;
  const long Wbase = (long)nb * 128 * 1024;

  f32x4 acc[4][4] = {};

  for (int kt = 0; kt < 1024; kt += BK) {
    __syncthreads();
#pragma unroll
    for (int q = 0; q < 2; ++q) {   // stage 128x32 of A and W (vector loads)
      int id  = q * 256 + t;
      int row = id >> 2;
      int c8  = (id & 3) << 3;
      bf16x8 va = *(const bf16x8*)(A + Abase + (long)row * 1024 + kt + c8);
      bf16x8 vb = *(const bf16x8*)(W + Wbase + (long)row * 1024 + kt + c8);
      *(bf16x8*)(&Al[row * LDA_ + c8]) = va;
      *(bf16x8*)(&Bl[row * LDA_ + c8]) = vb;
    }
    __syncthreads();
    bf16x8 af[4], bfr[4];
#pragma unroll
    for (int i = 0; i < 4; ++i) {
      af[i]  = *(const bf16x8*)(&Al[(wm * 64 + i * 16 + lr) * LDA_ + g * 8]);
      bfr[i] = *(const bf16x8*)(&Bl[(wn * 64 + i * 16 + lr) * LDA_ + g * 8]);
    }
#pragma unroll
    for (int i = 0; i < 4; ++i)
#pragma unroll
      for (int j = 0; j < 4; ++j)
        acc[i][j] = __builtin_amdgcn_mfma_f32_16x16x32_bf16(af[i], bfr[j], acc[i][j], 0, 0, 0);
  }

#pragma unroll
  for (int j = 0; j < 4; ++j) {
    int n = nb * 128 + wn * 64 + j * 16 + lr;
    float bv = bf2f(bias[n]);
#pragma unroll
    for (int i = 0; i < 4; ++i) {
      int m0 = mb * 128 + wm * 64 + i * 16 + g * 4;
      float v0 = (acc[i][j][0] + bv) * cscale;
      float v1 = (acc[i][j][1] + bv) * cscale;
      float v2 = (acc[i][j][2] + bv) * cscale;
      float v3 = (acc[i][j][3] + bv) * cscale;
      if (mode == 2) {            // V^T: [B,H,dk,S]; 4 consecutive s -> 8B store
        int b = m0 >> 11, s0 = m0 & (SEQ - 1);
        int h = n >> 6, d = n & (DK - 1);
        uint2 pk;
        pk.x = (unsigned)f2bf(v0) | ((unsigned)f2bf(v1) << 16);
        pk.y = (unsigned)f2bf(v2) | ((unsigned)f2bf(v3) << 16);
        *(uint2*)(&((unsigned short*)Cv)[((long)(b * NH + h) * DK + d) * SEQ + s0]) = pk;
      } else if (mode == 1) {     // [B,H,S,dk]
        int b = m0 >> 11, s0 = m0 & (SEQ - 1);
        int h = n >> 6, d = n & (DK - 1);
        unsigned short* p = &((unsigned short*)Cv)[(((long)(b * NH + h) * SEQ + s0) << 6) + d];
        p[0] = f2bf(v0); p[64] = f2bf(v1); p[128] = f2bf(v2); p[192] = f2bf(v3);
      } else {                    // row-major f32
        float* p = &((float*)Cv)[(long)m0 * DMODEL + n];
        p[0] = v0; p[DMODEL] = v1; p[2 * DMODEL] = v2; p[3 * DMODEL] = v3;
      }
    }
  }
}

// merged Q/K/V projection: 768 blocks, which = blockIdx.x >> 8
__global__ __launch_bounds__(256) void qkv_proj(const unsigned short* __restrict__ Aq,
                                                const unsigned short* __restrict__ Ak,
                                                const unsigned short* __restrict__ Av,
                                                const unsigned short* __restrict__ Wq,
                                                const unsigned short* __restrict__ Wk,
                                                const unsigned short* __restrict__ Wv,
                                                const unsigned short* __restrict__ bq,
                                                const unsigned short* __restrict__ bk,
                                                const unsigned short* __restrict__ bv,
                                                unsigned short* __restrict__ Cq,
                                                unsigned short* __restrict__ Ck,
                                                unsigned short* __restrict__ Cv) {
  __shared__ unsigned short Al[128 * LDA_];
  __shared__ unsigned short Bl[128 * LDA_];
  int which = blockIdx.x >> 8;
  int bid   = blockIdx.x & 255;
  const unsigned short* A = which == 0 ? Aq : (which == 1 ? Ak : Av);
  const unsigned short* W = which == 0 ? Wq : (which == 1 ? Wk : Wv);
  const unsigned short* b = which == 0 ? bq : (which == 1 ? bk : bv);
  unsigned short* C = which == 0 ? Cq : (which == 1 ? Ck : Cv);
  int   mode  = which == 2 ? 2 : 1;
  float scale = which == 0 ? QSCALE : 1.0f;
  gemm_body(A, W, b, C, mode, scale, bid, Al, Bl);
}

__global__ __launch_bounds__(256) void gemm_out(const unsigned short* __restrict__ A,
                                                const unsigned short* __restrict__ W,
                                                const unsigned short* __restrict__ bias,
                                                float* __restrict__ C) {
  __shared__ unsigned short Al[128 * LDA_];
  __shared__ unsigned short Bl[128 * LDA_];
  gemm_body(A, W, bias, C, 0, 1.0f, blockIdx.x, Al, Bl);
}

// ---------------------------------------------------------------- attention
// Q [B,H,S,64] (pre-scaled by QSCALE), K [B,H,S,64], VT [B,H,64,S] bf16.
// 32 q-rows per wave (two 16-row groups qh): K/V fragments reused by both
// groups -> 2x MFMA per ds_read. Barrier skeleton identical to r8/r9.
#define KVB 64
#define LD 72

__global__ __launch_bounds__(256) void attn(const unsigned short* __restrict__ Q,
                                            const unsigned short* __restrict__ K,
                                            const unsigned short* __restrict__ VT,
                                            const unsigned long long* __restrict__ pm,
                                            unsigned short* __restrict__ O) {
  __shared__ unsigned short Kl[KVB * LD];
  __shared__ unsigned short Vt[DK * LD];       // Vt[d][kv]
  __shared__ unsigned short Pl[4][32 * LD];    // per-wave 32 q-rows
  const int t    = threadIdx.x;
  const int lane = t & 63;
  const int w    = t >> 6;
  const int g    = lane >> 4, lr = lane & 15;
  const int qb   = blockIdx.x & 15;            // SEQ/128 = 16 q-blocks
  const int bh   = blockIdx.x >> 4;
  const int b    = bh >> 4, h = bh & 15;
  const long base = (long)bh * SEQ * DK;       // same flat size for K and VT
  const int q0   = qb * 128 + w * 32;          // wave's first q-row

  // Q fragments: qf[qh][kh] (B-operand of swapped QK^T)
  bf16x8 qf[2][2];
#pragma unroll
  for (int qh = 0; qh < 2; ++qh) {
    const unsigned short* qp = Q + base + (long)(q0 + qh * 16 + lr) * DK;
    qf[qh][0] = *(const bf16x8*)(qp + g * 8);
    qf[qh][1] = *(const bf16x8*)(qp + 32 + g * 8);
  }
  float mrun[2] = {NEGI, NEGI}, lrun[2] = {0.f, 0.f};  // log2-domain, q = q0+qh*16+lr
  f32x4 o[2][4] = {};

  for (int kt = 0; kt < SEQ / KVB; ++kt) {
    const int kvbase = kt * KVB;
    __syncthreads();
    // stage K rows [kv][64] — b128 loads/stores
#pragma unroll
    for (int p = 0; p < 2; ++p) {
      int id  = p * 256 + t;
      int row = id >> 3;
      int c8  = (id & 7) << 3;
      bf16x8 kv8 = *(const bf16x8*)(K + base + (long)(kvbase + row) * DK + c8);
      *(bf16x8*)(&Kl[row * LD + c8]) = kv8;
    }
    // stage V^T rows [d][kv-block] — b128 copies
#pragma unroll
    for (int p = 0; p < 2; ++p) {
      int id  = p * 256 + t;
      int row = id >> 3;
      int c8  = (id & 7) << 3;
      bf16x8 vv = *(const bf16x8*)(VT + base + (long)row * SEQ + kvbase + c8);
      *(bf16x8*)(&Vt[row * LD + c8]) = vv;
    }
    __syncthreads();

    // swapped scores: C[kv][q] for both q-groups; K frags read ONCE
    f32x4 sc[2][4];
#pragma unroll
    for (int c = 0; c < 4; ++c) {
      bf16x8 kf0 = *(const bf16x8*)(&Kl[(c * 16 + lr) * LD + g * 8]);
      bf16x8 kf1 = *(const bf16x8*)(&Kl[(c * 16 + lr) * LD + 32 + g * 8]);
#pragma unroll
      for (int qh = 0; qh < 2; ++qh) {
        f32x4 a = {};
        a = __builtin_amdgcn_mfma_f32_16x16x32_bf16(kf0, qf[qh][0], a, 0, 0, 0);
        a = __builtin_amdgcn_mfma_f32_16x16x32_bf16(kf1, qf[qh][1], a, 0, 0, 0);
        sc[qh][c] = a;
      }
    }

    unsigned short* P = &Pl[w][0];
#pragma unroll
    for (int qh = 0; qh < 2; ++qh) {
      const unsigned long long mw = pm[((long)b * SEQ + q0 + qh * 16 + lr) * 32 + kt];
      float s[4][4];
      float mt = NEGI;
#pragma unroll
      for (int c = 0; c < 4; ++c)
#pragma unroll
        for (int r = 0; r < 4; ++r) {
          int kvi = c * 16 + g * 4 + r;
          float v = ((mw >> kvi) & 1ull) ? sc[qh][c][r] : -1e9f;
          s[c][r] = v;
          mt = fmaxf(mt, v);
        }
      mt = fmaxf(mt, __shfl_xor(mt, 16, 64));
      mt = fmaxf(mt, __shfl_xor(mt, 32, 64));

      int need = __any(mt > mrun[qh] + 5.0f);   // defer-max (T13), log2 units
      float mn = mrun[qh], corr = 1.0f;
      if (need) { mn = fmaxf(mrun[qh], mt); corr = __builtin_amdgcn_exp2f(mrun[qh] - mn); mrun[qh] = mn; }

      float pf[4][4];
      float rs = 0.f;
#pragma unroll
      for (int c = 0; c < 4; ++c)
#pragma unroll
        for (int r = 0; r < 4; ++r) {
          float p_ = __builtin_amdgcn_exp2f(s[c][r] - mn);
          pf[c][r] = p_;
          rs += p_;
        }
      rs += __shfl_xor(rs, 16, 64);
      rs += __shfl_xor(rs, 32, 64);

      if (need) {
        lrun[qh] = lrun[qh] * corr + rs;
#pragma unroll
        for (int r = 0; r < 4; ++r) {
          float cq = __shfl(corr, (lane >> 4) * 4 + r, 64);  // corr of q-row g*4+r
#pragma unroll
          for (int dt = 0; dt < 4; ++dt) o[qh][dt][r] *= cq;
        }
      } else {
        lrun[qh] += rs;
      }

      // P store (A-fragment layout): row q-local = qh*16+lr, kv cols
#pragma unroll
      for (int c = 0; c < 4; ++c) {
        uint2 pk;
        pk.x = cvtpk(pf[c][0], pf[c][1]);
        pk.y = cvtpk(pf[c][2], pf[c][3]);
        *(uint2*)(&P[(qh * 16 + lr) * LD + c * 16 + g * 4]) = pk;
      }
    }
    __syncthreads();   // fence P stores vs vector re-reads (r8-proven)
    // PV: V fragments read ONCE, used by both q-groups
#pragma unroll
    for (int c32 = 0; c32 < 2; ++c32) {
      bf16x8 pf0 = *(const bf16x8*)(&P[lr * LD + c32 * 32 + g * 8]);
      bf16x8 pf1 = *(const bf16x8*)(&P[(16 + lr) * LD + c32 * 32 + g * 8]);
#pragma unroll
      for (int dt = 0; dt < 4; ++dt) {
        bf16x8 vf = *(const bf16x8*)(&Vt[(dt * 16 + lr) * LD + c32 * 32 + g * 8]);
        o[0][dt] = __builtin_amdgcn_mfma_f32_16x16x32_bf16(pf0, vf, o[0][dt], 0, 0, 0);
        o[1][dt] = __builtin_amdgcn_mfma_f32_16x16x32_bf16(pf1, vf, o[1][dt], 0, 0, 0);
      }
    }
  }
#pragma unroll
  for (int qh = 0; qh < 2; ++qh) {
    float inv = 1.0f / lrun[qh];
#pragma unroll
    for (int r = 0; r < 4; ++r) {
      float iq = __shfl(inv, (lane >> 4) * 4 + r, 64);
      int q = q0 + qh * 16 + g * 4 + r;
      unsigned short* op = O + ((long)(b * SEQ + q) * DMODEL) + h * DK;
#pragma unroll
      for (int dt = 0; dt < 4; ++dt) op[dt * 16 + lr] = f2bf(o[qh][dt][r] * iq);
    }
  }
}

// ---------------------------------------------------------------- launch
extern "C" void kernel_launch(void* const* d_in, const int* in_sizes, int n_in,
                              void* d_out, int out_size, void* d_ws, size_t ws_size,
                              hipStream_t stream) {
  const int* maskp = (const int*)d_in[3];
  float* out = (float*)d_out;

  char* ws = (char*)d_ws;
  const long MB = 1 << 20;
  unsigned long long* pm = (unsigned long long*)ws;             // 1 MB
  unsigned short* Qc  = (unsigned short*)(ws + 1 * MB);         // 8 MB each
  unsigned short* Kc  = (unsigned short*)(ws + 9 * MB);
  unsigned short* Vc  = (unsigned short*)(ws + 17 * MB);
  unsigned short* Wqc = (unsigned short*)(ws + 25 * MB);        // 2 MB each
  unsigned short* Wkc = (unsigned short*)(ws + 27 * MB);
  unsigned short* Wvc = (unsigned short*)(ws + 29 * MB);
  unsigned short* Woc = (unsigned short*)(ws + 31 * MB);
  unsigned short* bqc = (unsigned short*)(ws + 33 * MB);        // 2 KB each
  unsigned short* bkc = (unsigned short*)(ws + 33 * MB + 4096);
  unsigned short* bvc = (unsigned short*)(ws + 33 * MB + 8192);
  unsigned short* boc = (unsigned short*)(ws + 33 * MB + 12288);
  unsigned short* Qb  = (unsigned short*)(ws + 35 * MB);        // 8 MB each
  unsigned short* Kb  = (unsigned short*)(ws + 43 * MB);
  unsigned short* Vb  = (unsigned short*)(ws + 51 * MB);        // holds V^T
  unsigned short* Ab  = (unsigned short*)(ws + 59 * MB);

  const long nQKV8 = (long)MROWS * DMODEL / 8;   // 524288
  const long nW8   = (long)DMODEL * DMODEL / 8;  // 131072
  convert3<<<1536, 256, 0, stream>>>((const float*)d_in[0], (const float*)d_in[1],
                                     (const float*)d_in[2], Qc, Kc, Vc, nQKV8, 512);
  convert4<<<512, 256, 0, stream>>>((const float*)d_in[4], (const float*)d_in[6],
                                    (const float*)d_in[8], (const float*)d_in[10],
                                    Wqc, Wkc, Wvc, Woc, nW8, 128);
  convert4<<<4, 256, 0, stream>>>((const float*)d_in[5], (const float*)d_in[7],
                                  (const float*)d_in[9], (const float*)d_in[11],
                                  bqc, bkc, bvc, boc, DMODEL / 8, 1);

  const int nwords = BATCH * SEQ * (SEQ / 64);  // 131072
  pack_mask<<<512, 256, 0, stream>>>(maskp, pm, nwords);

  qkv_proj<<<768, 256, 0, stream>>>(Qc, Kc, Vc, Wqc, Wkc, Wvc,
                                    bqc, bkc, bvc, Qb, Kb, Vb);

  attn<<<BATCH * NH * (SEQ / 128), 256, 0, stream>>>(Qb, Kb, Vb, pm, Ab);

  gemm_out<<<256, 256, 0, stream>>>(Ab, Woc, boc, out);
}

// Round 13
// 200.150 us; speedup vs baseline: 25.5221x; 1.0679x over previous
//
#include <hip/hip_runtime.h>
#include <hip/hip_bf16.h>

#define NH 16
#define DK 64
#define SEQ 2048
#define DMODEL 1024
#define BATCH 2
#define MROWS (BATCH * SEQ) /* 4096 */

using bf16x8 = __attribute__((ext_vector_type(8))) short;
using f32x4  = __attribute__((ext_vector_type(4))) float;

#define NEGI (-1e30f)
#define QSCALE 0.18033688f  /* 0.125 * log2(e): folds 1/sqrt(dk) and exp->exp2 */

static __device__ __forceinline__ unsigned short f2bf(float x) {
  unsigned u = __builtin_bit_cast(unsigned, x);
  u += 0x7fffu + ((u >> 16) & 1u);   // RNE
  return (unsigned short)(u >> 16);
}
static __device__ __forceinline__ float bf2f(unsigned short h) {
  unsigned u = ((unsigned)h) << 16;
  return __builtin_bit_cast(float, u);
}
// packed f32x2 -> bf16x2 (lo = a, hi = b), single VALU inst
static __device__ __forceinline__ unsigned cvtpk(float a, float b) {
  unsigned r;
  asm("v_cvt_pk_bf16_f32 %0, %1, %2" : "=v"(r) : "v"(a), "v"(b));
  return r;
}

// ------------------------------------------------- converts (f32 -> bf16)
__global__ __launch_bounds__(256) void convert3(const float* __restrict__ s0,
                                                const float* __restrict__ s1,
                                                const float* __restrict__ s2,
                                                unsigned short* __restrict__ d0,
                                                unsigned short* __restrict__ d1,
                                                unsigned short* __restrict__ d2,
                                                long n8, int blkseg) {
  int seg = blockIdx.x / blkseg;
  int ib  = blockIdx.x % blkseg;
  const float* s = seg == 0 ? s0 : (seg == 1 ? s1 : s2);
  unsigned short* d = seg == 0 ? d0 : (seg == 1 ? d1 : d2);
  long i0 = (long)ib * blockDim.x + threadIdx.x;
  long stride = (long)blkseg * blockDim.x;
  for (long i = i0; i < n8; i += stride) {
    const float* p = s + i * 8;
    float4 a = *(const float4*)(p);
    float4 b = *(const float4*)(p + 4);
    bf16x8 v;
    v[0] = (short)f2bf(a.x); v[1] = (short)f2bf(a.y);
    v[2] = (short)f2bf(a.z); v[3] = (short)f2bf(a.w);
    v[4] = (short)f2bf(b.x); v[5] = (short)f2bf(b.y);
    v[6] = (short)f2bf(b.z); v[7] = (short)f2bf(b.w);
    *(bf16x8*)(d + i * 8) = v;
  }
}
__global__ __launch_bounds__(256) void convert4(const float* __restrict__ s0,
                                                const float* __restrict__ s1,
                                                const float* __restrict__ s2,
                                                const float* __restrict__ s3,
                                                unsigned short* __restrict__ d0,
                                                unsigned short* __restrict__ d1,
                                                unsigned short* __restrict__ d2,
                                                unsigned short* __restrict__ d3,
                                                long n8, int blkseg) {
  int seg = blockIdx.x / blkseg;
  int ib  = blockIdx.x % blkseg;
  const float* s = seg == 0 ? s0 : (seg == 1 ? s1 : (seg == 2 ? s2 : s3));
  unsigned short* d = seg == 0 ? d0 : (seg == 1 ? d1 : (seg == 2 ? d2 : d3));
  long i0 = (long)ib * blockDim.x + threadIdx.x;
  long stride = (long)blkseg * blockDim.x;
  for (long i = i0; i < n8; i += stride) {
    const float* p = s + i * 8;
    float4 a = *(const float4*)(p);
    float4 b = *(const float4*)(p + 4);
    bf16x8 v;
    v[0] = (short)f2bf(a.x); v[1] = (short)f2bf(a.y);
    v[2] = (short)f2bf(a.z); v[3] = (short)f2bf(a.w);
    v[4] = (short)f2bf(b.x); v[5] = (short)f2bf(b.y);
    v[6] = (short)f2bf(b.z); v[7] = (short)f2bf(b.w);
    *(bf16x8*)(d + i * 8) = v;
  }
}

// ---------------------------------------------------------------- pack mask
__global__ __launch_bounds__(256) void pack_mask(const int* __restrict__ mask,
                                                 unsigned long long* __restrict__ pm,
                                                 int nwords) {
  int wid  = (blockIdx.x * blockDim.x + threadIdx.x) >> 6;
  int lane = threadIdx.x & 63;
  int nw   = (gridDim.x * blockDim.x) >> 6;
  for (int w = wid; w < nwords; w += nw) {
    int v = mask[(long)w * 64 + lane];
    unsigned long long b = __ballot(v != 0);
    if (lane == 0) pm[w] = b;
  }
}

// ---------------------------------------------------------------- GEMM core
// C = (A @ W^T + bias) * cscale.  Proven 2-barrier skeleton, BK=64 (halved
// barrier count vs r10; 32 MFMA / 16 ds_read per K-step).
// mode 0: row-major f32.  mode 1: bf16 scatter [B,H,S,dk].
// mode 2: bf16 scatter-transposed [B,H,dk,S] with packed 8B stores.
#define BK 64
#define LDA2 72   // padded LDS row (elems): 144 B, 16B-aligned

static __device__ __forceinline__ void gemm_body(const unsigned short* __restrict__ A,
                                                 const unsigned short* __restrict__ W,
                                                 const unsigned short* __restrict__ bias,
                                                 void* __restrict__ Cv,
                                                 int mode, float cscale, int bid,
                                                 unsigned short* Al, unsigned short* Bl) {
  const int t    = threadIdx.x;
  const int lane = t & 63;
  const int w    = t >> 6;
  const int wm   = w >> 1, wn = w & 1;
  const int g    = lane >> 4, lr = lane & 15;
  const int nb   = bid & 7;
  const int mb   = bid >> 3;
  const long Abase = (long)mb * 128 * 1024;
  const long Wbase = (long)nb * 128 * 1024;

  f32x4 acc[4][4] = {};

  for (int kt = 0; kt < 1024; kt += BK) {
    __syncthreads();
#pragma unroll
    for (int q = 0; q < 4; ++q) {   // stage 128x64 of A and W (vector loads)
      int id  = q * 256 + t;
      int row = id >> 3;            // 0..127
      int c8  = (id & 7) << 3;      // 0..56
      bf16x8 va = *(const bf16x8*)(A + Abase + (long)row * 1024 + kt + c8);
      bf16x8 vb = *(const bf16x8*)(W + Wbase + (long)row * 1024 + kt + c8);
      *(bf16x8*)(&Al[row * LDA2 + c8]) = va;
      *(bf16x8*)(&Bl[row * LDA2 + c8]) = vb;
    }
    __syncthreads();
#pragma unroll
    for (int kh = 0; kh < 2; ++kh) {   // two k=32 halves per staged tile
      bf16x8 af[4], bfr[4];
#pragma unroll
      for (int i = 0; i < 4; ++i) {
        af[i]  = *(const bf16x8*)(&Al[(wm * 64 + i * 16 + lr) * LDA2 + kh * 32 + g * 8]);
        bfr[i] = *(const bf16x8*)(&Bl[(wn * 64 + i * 16 + lr) * LDA2 + kh * 32 + g * 8]);
      }
#pragma unroll
      for (int i = 0; i < 4; ++i)
#pragma unroll
        for (int j = 0; j < 4; ++j)
          acc[i][j] = __builtin_amdgcn_mfma_f32_16x16x32_bf16(af[i], bfr[j], acc[i][j], 0, 0, 0);
    }
  }

#pragma unroll
  for (int j = 0; j < 4; ++j) {
    int n = nb * 128 + wn * 64 + j * 16 + lr;
    float bv = bf2f(bias[n]);
#pragma unroll
    for (int i = 0; i < 4; ++i) {
      int m0 = mb * 128 + wm * 64 + i * 16 + g * 4;
      float v0 = (acc[i][j][0] + bv) * cscale;
      float v1 = (acc[i][j][1] + bv) * cscale;
      float v2 = (acc[i][j][2] + bv) * cscale;
      float v3 = (acc[i][j][3] + bv) * cscale;
      if (mode == 2) {            // V^T: [B,H,dk,S]; 4 consecutive s -> 8B store
        int b = m0 >> 11, s0 = m0 & (SEQ - 1);
        int h = n >> 6, d = n & (DK - 1);
        uint2 pk;
        pk.x = (unsigned)f2bf(v0) | ((unsigned)f2bf(v1) << 16);
        pk.y = (unsigned)f2bf(v2) | ((unsigned)f2bf(v3) << 16);
        *(uint2*)(&((unsigned short*)Cv)[((long)(b * NH + h) * DK + d) * SEQ + s0]) = pk;
      } else if (mode == 1) {     // [B,H,S,dk]
        int b = m0 >> 11, s0 = m0 & (SEQ - 1);
        int h = n >> 6, d = n & (DK - 1);
        unsigned short* p = &((unsigned short*)Cv)[(((long)(b * NH + h) * SEQ + s0) << 6) + d];
        p[0] = f2bf(v0); p[64] = f2bf(v1); p[128] = f2bf(v2); p[192] = f2bf(v3);
      } else {                    // row-major f32
        float* p = &((float*)Cv)[(long)m0 * DMODEL + n];
        p[0] = v0; p[DMODEL] = v1; p[2 * DMODEL] = v2; p[3 * DMODEL] = v3;
      }
    }
  }
}

// merged Q/K/V projection: 768 blocks, which = blockIdx.x >> 8
__global__ __launch_bounds__(256) void qkv_proj(const unsigned short* __restrict__ Aq,
                                                const unsigned short* __restrict__ Ak,
                                                const unsigned short* __restrict__ Av,
                                                const unsigned short* __restrict__ Wq,
                                                const unsigned short* __restrict__ Wk,
                                                const unsigned short* __restrict__ Wv,
                                                const unsigned short* __restrict__ bq,
                                                const unsigned short* __restrict__ bk,
                                                const unsigned short* __restrict__ bv,
                                                unsigned short* __restrict__ Cq,
                                                unsigned short* __restrict__ Ck,
                                                unsigned short* __restrict__ Cv) {
  __shared__ unsigned short Al[128 * LDA2];
  __shared__ unsigned short Bl[128 * LDA2];
  int which = blockIdx.x >> 8;
  int bid   = blockIdx.x & 255;
  const unsigned short* A = which == 0 ? Aq : (which == 1 ? Ak : Av);
  const unsigned short* W = which == 0 ? Wq : (which == 1 ? Wk : Wv);
  const unsigned short* b = which == 0 ? bq : (which == 1 ? bk : bv);
  unsigned short* C = which == 0 ? Cq : (which == 1 ? Ck : Cv);
  int   mode  = which == 2 ? 2 : 1;
  float scale = which == 0 ? QSCALE : 1.0f;
  gemm_body(A, W, b, C, mode, scale, bid, Al, Bl);
}

__global__ __launch_bounds__(256) void gemm_out(const unsigned short* __restrict__ A,
                                                const unsigned short* __restrict__ W,
                                                const unsigned short* __restrict__ bias,
                                                float* __restrict__ C) {
  __shared__ unsigned short Al[128 * LDA2];
  __shared__ unsigned short Bl[128 * LDA2];
  gemm_body(A, W, bias, C, 0, 1.0f, blockIdx.x, Al, Bl);
}

// ---------------------------------------------------------------- attention
// EXACT r10 kernel (twice-validated, incl. post-timing replays).
// Q [B,H,S,64] (pre-scaled by QSCALE), K [B,H,S,64], VT [B,H,64,S] bf16.
// 32 q-rows per wave (two 16-row groups qh); online softmax + defer-max.
#define KVB 64
#define LD 72

__global__ __launch_bounds__(256) void attn(const unsigned short* __restrict__ Q,
                                            const unsigned short* __restrict__ K,
                                            const unsigned short* __restrict__ VT,
                                            const unsigned long long* __restrict__ pm,
                                            unsigned short* __restrict__ O) {
  __shared__ unsigned short Kl[KVB * LD];
  __shared__ unsigned short Vt[DK * LD];       // Vt[d][kv]
  __shared__ unsigned short Pl[4][32 * LD];    // per-wave 32 q-rows
  const int t    = threadIdx.x;
  const int lane = t & 63;
  const int w    = t >> 6;
  const int g    = lane >> 4, lr = lane & 15;
  const int qb   = blockIdx.x & 15;            // SEQ/128 = 16 q-blocks
  const int bh   = blockIdx.x >> 4;
  const int b    = bh >> 4, h = bh & 15;
  const long base = (long)bh * SEQ * DK;       // same flat size for K and VT
  const int q0   = qb * 128 + w * 32;          // wave's first q-row

  // Q fragments: qf[qh][kh] (B-operand of swapped QK^T)
  bf16x8 qf[2][2];
#pragma unroll
  for (int qh = 0; qh < 2; ++qh) {
    const unsigned short* qp = Q + base + (long)(q0 + qh * 16 + lr) * DK;
    qf[qh][0] = *(const bf16x8*)(qp + g * 8);
    qf[qh][1] = *(const bf16x8*)(qp + 32 + g * 8);
  }
  float mrun[2] = {NEGI, NEGI}, lrun[2] = {0.f, 0.f};  // log2-domain, q = q0+qh*16+lr
  f32x4 o[2][4] = {};

  for (int kt = 0; kt < SEQ / KVB; ++kt) {
    const int kvbase = kt * KVB;
    __syncthreads();
    // stage K rows [kv][64] — b128 loads/stores
#pragma unroll
    for (int p = 0; p < 2; ++p) {
      int id  = p * 256 + t;
      int row = id >> 3;
      int c8  = (id & 7) << 3;
      bf16x8 kv8 = *(const bf16x8*)(K + base + (long)(kvbase + row) * DK + c8);
      *(bf16x8*)(&Kl[row * LD + c8]) = kv8;
    }
    // stage V^T rows [d][kv-block] — b128 copies
#pragma unroll
    for (int p = 0; p < 2; ++p) {
      int id  = p * 256 + t;
      int row = id >> 3;
      int c8  = (id & 7) << 3;
      bf16x8 vv = *(const bf16x8*)(VT + base + (long)row * SEQ + kvbase + c8);
      *(bf16x8*)(&Vt[row * LD + c8]) = vv;
    }
    __syncthreads();

    // swapped scores: C[kv][q] for both q-groups; K frags read ONCE
    f32x4 sc[2][4];
#pragma unroll
    for (int c = 0; c < 4; ++c) {
      bf16x8 kf0 = *(const bf16x8*)(&Kl[(c * 16 + lr) * LD + g * 8]);
      bf16x8 kf1 = *(const bf16x8*)(&Kl[(c * 16 + lr) * LD + 32 + g * 8]);
#pragma unroll
      for (int qh = 0; qh < 2; ++qh) {
        f32x4 a = {};
        a = __builtin_amdgcn_mfma_f32_16x16x32_bf16(kf0, qf[qh][0], a, 0, 0, 0);
        a = __builtin_amdgcn_mfma_f32_16x16x32_bf16(kf1, qf[qh][1], a, 0, 0, 0);
        sc[qh][c] = a;
      }
    }

    unsigned short* P = &Pl[w][0];
#pragma unroll
    for (int qh = 0; qh < 2; ++qh) {
      const unsigned long long mw = pm[((long)b * SEQ + q0 + qh * 16 + lr) * 32 + kt];
      float s[4][4];
      float mt = NEGI;
#pragma unroll
      for (int c = 0; c < 4; ++c)
#pragma unroll
        for (int r = 0; r < 4; ++r) {
          int kvi = c * 16 + g * 4 + r;
          float v = ((mw >> kvi) & 1ull) ? sc[qh][c][r] : -1e9f;
          s[c][r] = v;
          mt = fmaxf(mt, v);
        }
      mt = fmaxf(mt, __shfl_xor(mt, 16, 64));
      mt = fmaxf(mt, __shfl_xor(mt, 32, 64));

      int need = __any(mt > mrun[qh] + 5.0f);   // defer-max (T13), log2 units
      float mn = mrun[qh], corr = 1.0f;
      if (need) { mn = fmaxf(mrun[qh], mt); corr = __builtin_amdgcn_exp2f(mrun[qh] - mn); mrun[qh] = mn; }

      float pf[4][4];
      float rs = 0.f;
#pragma unroll
      for (int c = 0; c < 4; ++c)
#pragma unroll
        for (int r = 0; r < 4; ++r) {
          float p_ = __builtin_amdgcn_exp2f(s[c][r] - mn);
          pf[c][r] = p_;
          rs += p_;
        }
      rs += __shfl_xor(rs, 16, 64);
      rs += __shfl_xor(rs, 32, 64);

      if (need) {
        lrun[qh] = lrun[qh] * corr + rs;
#pragma unroll
        for (int r = 0; r < 4; ++r) {
          float cq = __shfl(corr, (lane >> 4) * 4 + r, 64);  // corr of q-row g*4+r
#pragma unroll
          for (int dt = 0; dt < 4; ++dt) o[qh][dt][r] *= cq;
        }
      } else {
        lrun[qh] += rs;
      }

      // P store (A-fragment layout): row q-local = qh*16+lr, kv cols
#pragma unroll
      for (int c = 0; c < 4; ++c) {
        uint2 pk;
        pk.x = cvtpk(pf[c][0], pf[c][1]);
        pk.y = cvtpk(pf[c][2], pf[c][3]);
        *(uint2*)(&P[(qh * 16 + lr) * LD + c * 16 + g * 4]) = pk;
      }
    }
    __syncthreads();   // fence P stores vs vector re-reads (r8-proven)
    // PV: V fragments read ONCE, used by both q-groups
#pragma unroll
    for (int c32 = 0; c32 < 2; ++c32) {
      bf16x8 pf0 = *(const bf16x8*)(&P[lr * LD + c32 * 32 + g * 8]);
      bf16x8 pf1 = *(const bf16x8*)(&P[(16 + lr) * LD + c32 * 32 + g * 8]);
#pragma unroll
      for (int dt = 0; dt < 4; ++dt) {
        bf16x8 vf = *(const bf16x8*)(&Vt[(dt * 16 + lr) * LD + c32 * 32 + g * 8]);
        o[0][dt] = __builtin_amdgcn_mfma_f32_16x16x32_bf16(pf0, vf, o[0][dt], 0, 0, 0);
        o[1][dt] = __builtin_amdgcn_mfma_f32_16x16x32_bf16(pf1, vf, o[1][dt], 0, 0, 0);
      }
    }
  }
#pragma unroll
  for (int qh = 0; qh < 2; ++qh) {
    float inv = 1.0f / lrun[qh];
#pragma unroll
    for (int r = 0; r < 4; ++r) {
      float iq = __shfl(inv, (lane >> 4) * 4 + r, 64);
      int q = q0 + qh * 16 + g * 4 + r;
      unsigned short* op = O + ((long)(b * SEQ + q) * DMODEL) + h * DK;
#pragma unroll
      for (int dt = 0; dt < 4; ++dt) op[dt * 16 + lr] = f2bf(o[qh][dt][r] * iq);
    }
  }
}

// ---------------------------------------------------------------- launch
extern "C" void kernel_launch(void* const* d_in, const int* in_sizes, int n_in,
                              void* d_out, int out_size, void* d_ws, size_t ws_size,
                              hipStream_t stream) {
  const int* maskp = (const int*)d_in[3];
  float* out = (float*)d_out;

  char* ws = (char*)d_ws;
  const long MB = 1 << 20;
  unsigned long long* pm = (unsigned long long*)ws;             // 1 MB
  unsigned short* Qc  = (unsigned short*)(ws + 1 * MB);         // 8 MB each
  unsigned short* Kc  = (unsigned short*)(ws + 9 * MB);
  unsigned short* Vc  = (unsigned short*)(ws + 17 * MB);
  unsigned short* Wqc = (unsigned short*)(ws + 25 * MB);        // 2 MB each
  unsigned short* Wkc = (unsigned short*)(ws + 27 * MB);
  unsigned short* Wvc = (unsigned short*)(ws + 29 * MB);
  unsigned short* Woc = (unsigned short*)(ws + 31 * MB);
  unsigned short* bqc = (unsigned short*)(ws + 33 * MB);        // 2 KB each
  unsigned short* bkc = (unsigned short*)(ws + 33 * MB + 4096);
  unsigned short* bvc = (unsigned short*)(ws + 33 * MB + 8192);
  unsigned short* boc = (unsigned short*)(ws + 33 * MB + 12288);
  unsigned short* Qb  = (unsigned short*)(ws + 35 * MB);        // 8 MB each
  unsigned short* Kb  = (unsigned short*)(ws + 43 * MB);
  unsigned short* Vb  = (unsigned short*)(ws + 51 * MB);        // holds V^T
  unsigned short* Ab  = (unsigned short*)(ws + 59 * MB);

  const long nQKV8 = (long)MROWS * DMODEL / 8;   // 524288
  const long nW8   = (long)DMODEL * DMODEL / 8;  // 131072
  convert3<<<1536, 256, 0, stream>>>((const float*)d_in[0], (const float*)d_in[1],
                                     (const float*)d_in[2], Qc, Kc, Vc, nQKV8, 512);
  convert4<<<512, 256, 0, stream>>>((const float*)d_in[4], (const float*)d_in[6],
                                    (const float*)d_in[8], (const float*)d_in[10],
                                    Wqc, Wkc, Wvc, Woc, nW8, 128);
  convert4<<<4, 256, 0, stream>>>((const float*)d_in[5], (const float*)d_in[7],
                                  (const float*)d_in[9], (const float*)d_in[11],
                                  bqc, bkc, bvc, boc, DMODEL / 8, 1);

  const int nwords = BATCH * SEQ * (SEQ / 64);  // 131072
  pack_mask<<<512, 256, 0, stream>>>(maskp, pm, nwords);

  qkv_proj<<<768, 256, 0, stream>>>(Qc, Kc, Vc, Wqc, Wkc, Wvc,
                                    bqc, bkc, bvc, Qb, Kb, Vb);

  attn<<<BATCH * NH * (SEQ / 128), 256, 0, stream>>>(Qb, Kb, Vb, pm, Ab);

  gemm_out<<<256, 256, 0, stream>>>(Ab, Woc, boc, out);
}